// Round 1
// baseline (1283.493 us; speedup 1.0000x reference)
//
#include <hip/hip_runtime.h>
#include <math.h>

// GraphRespiratory: 2-layer GAT (edge features, concat=False) + factor graph.
// N=50000, E=800000, IN=128, HID=OUT=64, H=2, NC=5, EC=2, NUM_ITER=2, GAMMA=1.

static inline int cdiv_i(long long a, long long b) { return (int)((a + b - 1) / b); }

__device__ __forceinline__ void atomic_max_float(float* addr, float val) {
  if (val >= 0.0f) atomicMax((int*)addr, __float_as_int(val));
  else atomicMin((unsigned int*)addr, __float_as_uint(val));
}

// ---------- utility ----------
__global__ void k_fill(float* __restrict__ p, float v, int n) {
  int i = blockIdx.x * blockDim.x + threadIdx.x;
  if (i < n) p[i] = v;
}

// consts: [0..3] w_e1[h][k], [4..7] w_e2[h][k], [8] avg_ef, [9] avg_nf
__global__ void k_prep_consts(const float* __restrict__ We1, const float* __restrict__ att_e1,
                              const float* __restrict__ We2, const float* __restrict__ att_e2,
                              const float* __restrict__ node_fw, const float* __restrict__ edge_fw,
                              float* __restrict__ consts) {
  if (blockIdx.x != 0 || threadIdx.x != 0) return;
  for (int h = 0; h < 2; ++h) {
    for (int k = 0; k < 2; ++k) {
      float s1 = 0.f, s2 = 0.f;
      for (int c = 0; c < 64; ++c) {
        s1 += We1[k * 128 + h * 64 + c] * att_e1[h * 64 + c];
        s2 += We2[k * 128 + h * 64 + c] * att_e2[h * 64 + c];
      }
      consts[h * 2 + k] = s1;
      consts[4 + h * 2 + k] = s2;
    }
  }
  float ef = 0.f;                      // edge_fw is [EC=2, NC=5]; mean of [1:,1:]
  for (int j = 1; j < 5; ++j) ef += edge_fw[5 + j];
  consts[8] = ef * 0.25f;
  float nf = 0.f;                      // node_fw is [NC=5, EC=2]; mean of [1:,1:]
  for (int i = 1; i < 5; ++i) nf += node_fw[i * 2 + 1];
  consts[9] = nf * 0.25f;
}

// degrees (by dst for self-loop attr; by src+dst for factor graph) + loop_attr sums
__global__ void k_degrees(const int* __restrict__ src, const int* __restrict__ dst,
                          const float* __restrict__ eattr,
                          float* __restrict__ deg_dst, float* __restrict__ loop_sum,
                          float* __restrict__ deg_fg, int E) {
  int e = blockIdx.x * blockDim.x + threadIdx.x;
  if (e >= E) return;
  int s = src[e], d = dst[e];
  float e0 = eattr[2 * e], e1 = eattr[2 * e + 1];
  atomicAdd(&deg_dst[d], 1.0f);
  atomicAdd(&loop_sum[2 * d], e0);
  atomicAdd(&loop_sum[2 * d + 1], e1);
  atomicAdd(&deg_fg[s], 1.0f);
  atomicAdd(&deg_fg[d], 1.0f);
}

__global__ void k_loop_fin(float* __restrict__ loop_attr, const float* __restrict__ deg_dst, int N) {
  int n = blockIdx.x * blockDim.x + threadIdx.x;
  if (n >= N) return;
  float inv = 1.0f / fmaxf(deg_dst[n], 1.0f);
  loop_attr[2 * n] *= inv;
  loop_attr[2 * n + 1] *= inv;
}

// C[N,128] = A[N,K] @ W[K,128], f32. W fully staged in LDS, 32 rows/block.
template<int K>
__global__ __launch_bounds__(256)
void k_gemm(const float* __restrict__ A, const float* __restrict__ W,
            float* __restrict__ C, int N) {
  __shared__ float Wl[K * 128];
  __shared__ float Al[32 * K];
  int tid = threadIdx.x;
  for (int i = tid * 4; i < K * 128; i += 256 * 4)
    *(float4*)&Wl[i] = *(const float4*)&W[i];
  int row0 = blockIdx.x * 32;
  for (int i = tid * 4; i < 32 * K; i += 256 * 4) {
    int r = i / K, c = i % K;
    int gr = row0 + r;
    float4 v = make_float4(0.f, 0.f, 0.f, 0.f);
    if (gr < N) v = *(const float4*)&A[(long long)gr * K + c];
    *(float4*)&Al[r * K + c] = v;
  }
  __syncthreads();
  int col = tid & 127;
  int rbase = (tid >> 7) * 16;
  float acc[16];
#pragma unroll
  for (int r = 0; r < 16; ++r) acc[r] = 0.f;
  for (int k = 0; k < K; ++k) {
    float w = Wl[k * 128 + col];
#pragma unroll
    for (int r = 0; r < 16; ++r) acc[r] += Al[(rbase + r) * K + k] * w;
  }
#pragma unroll
  for (int r = 0; r < 16; ++r) {
    int gr = row0 + rbase + r;
    if (gr < N) C[(long long)gr * 128 + col] = acc[r];
  }
}

// per-node attention scalars: a_s[n,h] = h[n,h,:]·att_s[h,:], a_d likewise. One wave/node.
__global__ void k_att_nodes(const float* __restrict__ h,
                            const float* __restrict__ atts, const float* __restrict__ attd,
                            float* __restrict__ a_s, float* __restrict__ a_d, int N) {
  int idx = blockIdx.x * blockDim.x + threadIdx.x;
  int n = idx >> 6, lane = idx & 63;
  if (n >= N) return;
  float v0 = h[(long long)n * 128 + lane];
  float v1 = h[(long long)n * 128 + 64 + lane];
  float ps0 = v0 * atts[lane];
  float ps1 = v1 * atts[64 + lane];
  float pd0 = v0 * attd[lane];
  float pd1 = v1 * attd[64 + lane];
  for (int off = 32; off; off >>= 1) {
    ps0 += __shfl_down(ps0, off);
    ps1 += __shfl_down(ps1, off);
    pd0 += __shfl_down(pd0, off);
    pd1 += __shfl_down(pd1, off);
  }
  if (lane == 0) {
    a_s[2 * n] = ps0; a_s[2 * n + 1] = ps1;
    a_d[2 * n] = pd0; a_d[2 * n + 1] = pd1;
  }
}

// edge pass 1: a = leaky_relu(a_s[s]+a_d[d]+a_e, 0.2); atomicMax amax[d]
__global__ void k_edge1(const int* __restrict__ src, const int* __restrict__ dst,
                        const float* __restrict__ eattr, const float* __restrict__ loop_attr,
                        const float* __restrict__ a_s, const float* __restrict__ a_d,
                        const float* __restrict__ we,
                        float* __restrict__ a, float* __restrict__ amax, int E, int N) {
  int e = blockIdx.x * blockDim.x + threadIdx.x;
  if (e >= E + N) return;
  int s, d; float e0, e1;
  if (e < E) { s = src[e]; d = dst[e]; e0 = eattr[2 * e]; e1 = eattr[2 * e + 1]; }
  else { s = d = e - E; e0 = loop_attr[2 * s]; e1 = loop_attr[2 * s + 1]; }
  float x0 = a_s[2 * s] + a_d[2 * d] + e0 * we[0] + e1 * we[1];
  float x1 = a_s[2 * s + 1] + a_d[2 * d + 1] + e0 * we[2] + e1 * we[3];
  x0 = x0 >= 0.f ? x0 : 0.2f * x0;
  x1 = x1 >= 0.f ? x1 : 0.2f * x1;
  a[2 * e] = x0; a[2 * e + 1] = x1;
  atomic_max_float(&amax[2 * d], x0);
  atomic_max_float(&amax[2 * d + 1], x1);
}

// edge pass 2: ea = exp(a - amax[d]) (in place); atomicAdd denom[d]
__global__ void k_edge2(const int* __restrict__ dst, const float* __restrict__ amax,
                        float* __restrict__ a, float* __restrict__ denom, int E, int N) {
  int e = blockIdx.x * blockDim.x + threadIdx.x;
  if (e >= E + N) return;
  int d = (e < E) ? dst[e] : e - E;
  float ea0 = expf(a[2 * e] - amax[2 * d]);
  float ea1 = expf(a[2 * e + 1] - amax[2 * d + 1]);
  a[2 * e] = ea0; a[2 * e + 1] = ea1;
  atomicAdd(&denom[2 * d], ea0);
  atomicAdd(&denom[2 * d + 1], ea1);
}

// edge pass 3 (wave/edge): agg[d,c] += 0.5*(alpha0*h[s,0,c] + alpha1*h[s,1,c])
__global__ void k_edge3(const int* __restrict__ src, const int* __restrict__ dst,
                        const float* __restrict__ ea, const float* __restrict__ denom,
                        const float* __restrict__ h, float* __restrict__ agg, int E, int N) {
  long long idx = (long long)blockIdx.x * blockDim.x + threadIdx.x;
  int e = (int)(idx >> 6), lane = (int)(idx & 63);
  if (e >= E + N) return;
  int s, d;
  if (e < E) { s = src[e]; d = dst[e]; } else { s = d = e - E; }
  float al0 = ea[2 * e]     / (denom[2 * d]     + 1e-16f);
  float al1 = ea[2 * e + 1] / (denom[2 * d + 1] + 1e-16f);
  float v = 0.5f * (al0 * h[(long long)s * 128 + lane] + al1 * h[(long long)s * 128 + 64 + lane]);
  atomicAdd(&agg[(long long)d * 64 + lane], v);
}

template<bool RELU>
__global__ void k_bias_act(const float* __restrict__ in, const float* __restrict__ b,
                           float* __restrict__ o, int total) {
  int i = blockIdx.x * blockDim.x + threadIdx.x;
  if (i >= total) return;
  float v = in[i] + b[i & 63];
  if (RELU) v = fmaxf(v, 0.f);
  o[i] = v;
}

// per-node heads: p_n = softmax(h@Wn + bn); r = h@Wec (bec added per-edge). One wave/node.
__global__ void k_head(const float* __restrict__ hh, const float* __restrict__ Wn,
                       const float* __restrict__ bn, const float* __restrict__ Wec,
                       float* __restrict__ p_n, float* __restrict__ r, int N) {
  int idx = blockIdx.x * blockDim.x + threadIdx.x;
  int n = idx >> 6, lane = idx & 63;
  if (n >= N) return;
  float v = hh[(long long)n * 64 + lane];
  float p[7];
#pragma unroll
  for (int j = 0; j < 5; ++j) p[j] = v * Wn[lane * 5 + j];
  p[5] = v * Wec[lane * 2];
  p[6] = v * Wec[lane * 2 + 1];
  for (int off = 32; off; off >>= 1) {
#pragma unroll
    for (int j = 0; j < 7; ++j) p[j] += __shfl_down(p[j], off);
  }
  if (lane == 0) {
    float l[5]; float m = -1e30f;
#pragma unroll
    for (int j = 0; j < 5; ++j) { l[j] = p[j] + bn[j]; m = fmaxf(m, l[j]); }
    float ssum = 0.f;
#pragma unroll
    for (int j = 0; j < 5; ++j) { l[j] = expf(l[j] - m); ssum += l[j]; }
    float inv = 1.0f / ssum;
#pragma unroll
    for (int j = 0; j < 5; ++j) p_n[5 * n + j] = l[j] * inv;
    r[2 * n] = p[5];
    r[2 * n + 1] = p[6];
  }
}

// factor-graph edge update (+ eab scatter). FIRST: build p_e from logits. LAST: emit log.
template<bool FIRST, bool LAST>
__global__ void k_fg_edge(const int* __restrict__ src, const int* __restrict__ dst,
                          const float* __restrict__ r, const float* __restrict__ bec,
                          const float* __restrict__ p_n, float* __restrict__ p_e,
                          float* __restrict__ s_acc, const float* __restrict__ consts,
                          float* __restrict__ out_e, int E) {
  int e = blockIdx.x * blockDim.x + threadIdx.x;
  if (e >= E) return;
  int s = src[e], d = dst[e];
  float pe0, pe1;
  if (FIRST) {
    float l0 = 0.5f * (r[2 * s] + r[2 * d]) + bec[0];
    float l1 = 0.5f * (r[2 * s + 1] + r[2 * d + 1]) + bec[1];
    float m = fmaxf(l0, l1);
    float x0 = expf(l0 - m), x1 = expf(l1 - m);
    float inv = 1.0f / (x0 + x1);
    pe0 = x0 * inv; pe1 = x1 * inv;
  } else {
    pe0 = p_e[2 * e]; pe1 = p_e[2 * e + 1];
  }
  float nab_s = 1.0f - p_n[5 * s];
  float nab_d = 1.0f - p_n[5 * d];
  float ena = fmaxf(nab_s, nab_d);
  float f = 1.0f + ena * consts[8];           // GAMMA = 1
  pe1 *= f;
  float inv2 = 1.0f / (pe0 + pe1);
  pe0 *= inv2; pe1 *= inv2;
  if (LAST) {
    out_e[2 * e] = logf(pe0 + 1e-9f);
    out_e[2 * e + 1] = logf(pe1 + 1e-9f);
  } else {
    p_e[2 * e] = pe0; p_e[2 * e + 1] = pe1;
  }
  float eab = pe1;                            // 1 - pe0
  atomicAdd(&s_acc[s], eab);
  atomicAdd(&s_acc[d], eab);
}

template<bool LAST>
__global__ void k_fg_node(float* __restrict__ p_n, const float* __restrict__ s_acc,
                          const float* __restrict__ deg_fg, const float* __restrict__ consts,
                          float* __restrict__ out_n, int N) {
  int n = blockIdx.x * blockDim.x + threadIdx.x;
  if (n >= N) return;
  float mean = s_acc[n] / (deg_fg[n] + 1e-6f);
  float f = 1.0f + mean * consts[9];          // GAMMA = 1
  float p0 = p_n[5 * n];
  float p1 = p_n[5 * n + 1] * f;
  float p2 = p_n[5 * n + 2] * f;
  float p3 = p_n[5 * n + 3] * f;
  float p4 = p_n[5 * n + 4] * f;
  float inv = 1.0f / (p0 + p1 + p2 + p3 + p4);
  p0 *= inv; p1 *= inv; p2 *= inv; p3 *= inv; p4 *= inv;
  if (LAST) {
    out_n[5 * n]     = logf(p0 + 1e-9f);
    out_n[5 * n + 1] = logf(p1 + 1e-9f);
    out_n[5 * n + 2] = logf(p2 + 1e-9f);
    out_n[5 * n + 3] = logf(p3 + 1e-9f);
    out_n[5 * n + 4] = logf(p4 + 1e-9f);
  } else {
    p_n[5 * n]     = p0;
    p_n[5 * n + 1] = p1;
    p_n[5 * n + 2] = p2;
    p_n[5 * n + 3] = p3;
    p_n[5 * n + 4] = p4;
  }
}

extern "C" void kernel_launch(void* const* d_in, const int* in_sizes, int n_in,
                              void* d_out, int out_size, void* d_ws, size_t ws_size,
                              hipStream_t stream) {
  const float* x      = (const float*)d_in[0];
  const int*   ei     = (const int*)d_in[1];
  const float* eattr  = (const float*)d_in[2];
  const float* W1     = (const float*)d_in[3];
  const float* atts1  = (const float*)d_in[4];
  const float* attd1  = (const float*)d_in[5];
  const float* We1    = (const float*)d_in[6];
  const float* atte1  = (const float*)d_in[7];
  const float* b1     = (const float*)d_in[8];
  const float* W2     = (const float*)d_in[9];
  const float* atts2  = (const float*)d_in[10];
  const float* attd2  = (const float*)d_in[11];
  const float* We2    = (const float*)d_in[12];
  const float* atte2  = (const float*)d_in[13];
  const float* b2     = (const float*)d_in[14];
  const float* Wn     = (const float*)d_in[15];
  const float* bn     = (const float*)d_in[16];
  const float* Wec    = (const float*)d_in[17];
  const float* bec    = (const float*)d_in[18];
  const float* nodefw = (const float*)d_in[19];
  const float* edgefw = (const float*)d_in[20];

  const int N = in_sizes[0] / 128;
  const int E = in_sizes[1] / 2;
  const int EL = E + N;  // edges incl. self-loops
  const int* src = ei;
  const int* dst = ei + E;

  float* out_n = (float*)d_out;
  float* out_e = out_n + (long long)N * 5;

  // ---- workspace carve (f32) ----
  size_t off = 0;
  float* base = (float*)d_ws;
  auto carve = [&](size_t nelem) { float* p = base + off; off += (nelem + 3) & ~(size_t)3; return p; };
  float* h         = carve((size_t)N * 128);
  float* x2        = carve((size_t)N * 64);   // relu(out1)+b1; later reused as out2
  float* agg       = carve((size_t)N * 64);
  float* a_s       = carve((size_t)N * 2);
  float* a_d       = carve((size_t)N * 2);
  float* amax      = carve((size_t)N * 2);
  float* denom     = carve((size_t)N * 2);
  float* deg_dst   = carve((size_t)N);
  float* deg_fg    = carve((size_t)N);
  float* loop_attr = carve((size_t)N * 2);
  float* a_ea      = carve((size_t)EL * 2);
  float* p_n       = carve((size_t)N * 5);
  float* r         = carve((size_t)N * 2);
  float* p_e       = carve((size_t)E * 2);
  float* s_acc     = carve((size_t)N);
  float* consts    = carve(16);
  if (off * sizeof(float) > ws_size) return;  // insufficient scratch: fail loudly

  const int B = 256;
  const int gE  = cdiv_i(E, B);
  const int gEL = cdiv_i(EL, B);
  const int gN  = cdiv_i(N, B);
  const int gNW = cdiv_i((long long)N * 64, B);   // wave-per-node kernels
  const int gELW = cdiv_i((long long)EL * 64, B); // wave-per-edge kernels
  const int gNC = cdiv_i((long long)N * 64, B);

  // ---- graph-invariant prep ----
  hipMemsetAsync(deg_dst, 0, (size_t)N * 4, stream);
  hipMemsetAsync(deg_fg, 0, (size_t)N * 4, stream);
  hipMemsetAsync(loop_attr, 0, (size_t)N * 8, stream);
  k_prep_consts<<<1, 64, 0, stream>>>(We1, atte1, We2, atte2, nodefw, edgefw, consts);
  k_degrees<<<gE, B, 0, stream>>>(src, dst, eattr, deg_dst, loop_attr, deg_fg, E);
  k_loop_fin<<<gN, B, 0, stream>>>(loop_attr, deg_dst, N);

  // ---- GAT layer 1 ----
  k_gemm<128><<<cdiv_i(N, 32), 256, 0, stream>>>(x, W1, h, N);
  k_att_nodes<<<gNW, B, 0, stream>>>(h, atts1, attd1, a_s, a_d, N);
  k_fill<<<cdiv_i((long long)N * 2, B), B, 0, stream>>>(amax, -1e30f, N * 2);
  hipMemsetAsync(denom, 0, (size_t)N * 8, stream);
  hipMemsetAsync(agg, 0, (size_t)N * 64 * 4, stream);
  k_edge1<<<gEL, B, 0, stream>>>(src, dst, eattr, loop_attr, a_s, a_d, consts, a_ea, amax, E, N);
  k_edge2<<<gEL, B, 0, stream>>>(dst, amax, a_ea, denom, E, N);
  k_edge3<<<gELW, B, 0, stream>>>(src, dst, a_ea, denom, h, agg, E, N);
  k_bias_act<true><<<gNC, B, 0, stream>>>(agg, b1, x2, N * 64);

  // ---- GAT layer 2 ----
  k_gemm<64><<<cdiv_i(N, 32), 256, 0, stream>>>(x2, W2, h, N);
  k_att_nodes<<<gNW, B, 0, stream>>>(h, atts2, attd2, a_s, a_d, N);
  k_fill<<<cdiv_i((long long)N * 2, B), B, 0, stream>>>(amax, -1e30f, N * 2);
  hipMemsetAsync(denom, 0, (size_t)N * 8, stream);
  hipMemsetAsync(agg, 0, (size_t)N * 64 * 4, stream);
  k_edge1<<<gEL, B, 0, stream>>>(src, dst, eattr, loop_attr, a_s, a_d, consts + 4, a_ea, amax, E, N);
  k_edge2<<<gEL, B, 0, stream>>>(dst, amax, a_ea, denom, E, N);
  k_edge3<<<gELW, B, 0, stream>>>(src, dst, a_ea, denom, h, agg, E, N);
  k_bias_act<false><<<gNC, B, 0, stream>>>(agg, b2, x2, N * 64);  // x2 now = h (final node emb)

  // ---- heads ----
  k_head<<<gNW, B, 0, stream>>>(x2, Wn, bn, Wec, p_n, r, N);

  // ---- factor graph, 2 iterations ----
  hipMemsetAsync(s_acc, 0, (size_t)N * 4, stream);
  k_fg_edge<true, false><<<gE, B, 0, stream>>>(src, dst, r, bec, p_n, p_e, s_acc, consts, nullptr, E);
  k_fg_node<false><<<gN, B, 0, stream>>>(p_n, s_acc, deg_fg, consts, nullptr, N);
  hipMemsetAsync(s_acc, 0, (size_t)N * 4, stream);
  k_fg_edge<false, true><<<gE, B, 0, stream>>>(src, dst, r, bec, p_n, p_e, s_acc, consts, out_e, E);
  k_fg_node<true><<<gN, B, 0, stream>>>(p_n, s_acc, deg_fg, consts, out_n, N);
}

// Round 2
// 1099.498 us; speedup vs baseline: 1.1673x; 1.1673x over previous
//
#include <hip/hip_runtime.h>
#include <math.h>

// GraphRespiratory: 2-layer GAT (edge features, concat=False) + factor graph.
// N=50000, E=800000, IN=128, HID=OUT=64, H=2, NC=5, EC=2, NUM_ITER=2, GAMMA=1.
//
// R1 changes vs R0:
//  - k_degrees: packed nd4[n]={deg_dst,loop0,loop1,_} (1 line) + deg_src (1 line)
//    instead of 5 scattered lines/edge. deg_fg computed in finalize.
//  - Softmax shift-invariance: dropped segment-max (amax) pass + k_edge2 re-read
//    pass entirely; k_edge12 computes a -> exp -> denom atomics in one pass.
//  - a_s/a_d packed into asd[n][4]: one 16B gather per edge endpoint.

static inline int cdiv_i(long long a, long long b) { return (int)((a + b - 1) / b); }

// consts: [0..3] w_e1[h][k], [4..7] w_e2[h][k], [8] avg_ef, [9] avg_nf
__global__ void k_prep_consts(const float* __restrict__ We1, const float* __restrict__ att_e1,
                              const float* __restrict__ We2, const float* __restrict__ att_e2,
                              const float* __restrict__ node_fw, const float* __restrict__ edge_fw,
                              float* __restrict__ consts) {
  if (blockIdx.x != 0 || threadIdx.x != 0) return;
  for (int h = 0; h < 2; ++h) {
    for (int k = 0; k < 2; ++k) {
      float s1 = 0.f, s2 = 0.f;
      for (int c = 0; c < 64; ++c) {
        s1 += We1[k * 128 + h * 64 + c] * att_e1[h * 64 + c];
        s2 += We2[k * 128 + h * 64 + c] * att_e2[h * 64 + c];
      }
      consts[h * 2 + k] = s1;
      consts[4 + h * 2 + k] = s2;
    }
  }
  float ef = 0.f;                      // edge_fw is [EC=2, NC=5]; mean of [1:,1:]
  for (int j = 1; j < 5; ++j) ef += edge_fw[5 + j];
  consts[8] = ef * 0.25f;
  float nf = 0.f;                      // node_fw is [NC=5, EC=2]; mean of [1:,1:]
  for (int i = 1; i < 5; ++i) nf += node_fw[i * 2 + 1];
  consts[9] = nf * 0.25f;
}

// degrees + loop_attr sums. nd4[n] = {deg_dst, loop_sum0, loop_sum1, unused}
// (one 16B slot -> one cache line per dst), deg_src[n] separate (one line per src).
__global__ void k_degrees(const int* __restrict__ src, const int* __restrict__ dst,
                          const float* __restrict__ eattr2,
                          float* __restrict__ nd4, float* __restrict__ deg_src, int E) {
  int e = blockIdx.x * blockDim.x + threadIdx.x;
  if (e >= E) return;
  int s = src[e], d = dst[e];
  float e0 = eattr2[2 * e], e1 = eattr2[2 * e + 1];
  atomicAdd(&nd4[4 * d], 1.0f);
  atomicAdd(&nd4[4 * d + 1], e0);
  atomicAdd(&nd4[4 * d + 2], e1);
  atomicAdd(&deg_src[s], 1.0f);
}

// finalize: loop_attr (normalized, in place in nd4) and deg_fg = deg_src + deg_dst.
__global__ void k_loop_fin(float* __restrict__ nd4, const float* __restrict__ deg_src,
                           float* __restrict__ deg_fg, int N) {
  int n = blockIdx.x * blockDim.x + threadIdx.x;
  if (n >= N) return;
  float degd = nd4[4 * n];
  float inv = 1.0f / fmaxf(degd, 1.0f);
  nd4[4 * n + 1] *= inv;
  nd4[4 * n + 2] *= inv;
  deg_fg[n] = degd + deg_src[n];
}

// C[N,128] = A[N,K] @ W[K,128], f32. W fully staged in LDS, 32 rows/block.
template<int K>
__global__ __launch_bounds__(256)
void k_gemm(const float* __restrict__ A, const float* __restrict__ W,
            float* __restrict__ C, int N) {
  __shared__ float Wl[K * 128];
  __shared__ float Al[32 * K];
  int tid = threadIdx.x;
  for (int i = tid * 4; i < K * 128; i += 256 * 4)
    *(float4*)&Wl[i] = *(const float4*)&W[i];
  int row0 = blockIdx.x * 32;
  for (int i = tid * 4; i < 32 * K; i += 256 * 4) {
    int r = i / K, c = i % K;
    int gr = row0 + r;
    float4 v = make_float4(0.f, 0.f, 0.f, 0.f);
    if (gr < N) v = *(const float4*)&A[(long long)gr * K + c];
    *(float4*)&Al[r * K + c] = v;
  }
  __syncthreads();
  int col = tid & 127;
  int rbase = (tid >> 7) * 16;
  float acc[16];
#pragma unroll
  for (int r = 0; r < 16; ++r) acc[r] = 0.f;
  for (int k = 0; k < K; ++k) {
    float w = Wl[k * 128 + col];
#pragma unroll
    for (int r = 0; r < 16; ++r) acc[r] += Al[(rbase + r) * K + k] * w;
  }
#pragma unroll
  for (int r = 0; r < 16; ++r) {
    int gr = row0 + rbase + r;
    if (gr < N) C[(long long)gr * 128 + col] = acc[r];
  }
}

// per-node attention scalars packed: asd[n] = {as0, as1, ad0, ad1}. One wave/node.
__global__ void k_att_nodes(const float* __restrict__ h,
                            const float* __restrict__ atts, const float* __restrict__ attd,
                            float* __restrict__ asd, int N) {
  int idx = blockIdx.x * blockDim.x + threadIdx.x;
  int n = idx >> 6, lane = idx & 63;
  if (n >= N) return;
  float v0 = h[(long long)n * 128 + lane];
  float v1 = h[(long long)n * 128 + 64 + lane];
  float ps0 = v0 * atts[lane];
  float ps1 = v1 * atts[64 + lane];
  float pd0 = v0 * attd[lane];
  float pd1 = v1 * attd[64 + lane];
  for (int off = 32; off; off >>= 1) {
    ps0 += __shfl_down(ps0, off);
    ps1 += __shfl_down(ps1, off);
    pd0 += __shfl_down(pd0, off);
    pd1 += __shfl_down(pd1, off);
  }
  if (lane == 0) {
    asd[4 * n] = ps0; asd[4 * n + 1] = ps1;
    asd[4 * n + 2] = pd0; asd[4 * n + 3] = pd1;
  }
}

// fused edge pass: a = leaky_relu(as[s]+ad[d]+a_e); ea = exp(a) (no max shift —
// softmax is shift-invariant and |a| is O(10) so exp can't overflow f32);
// atomicAdd denom[d] (float2 slot, one line).
__global__ void k_edge12(const int* __restrict__ src, const int* __restrict__ dst,
                         const float* __restrict__ eattr2, const float* __restrict__ nd4,
                         const float* __restrict__ asd, const float* __restrict__ we,
                         float* __restrict__ ea, float* __restrict__ denom, int E, int N) {
  int e = blockIdx.x * blockDim.x + threadIdx.x;
  if (e >= E + N) return;
  int s, d; float e0, e1;
  if (e < E) {
    s = src[e]; d = dst[e];
    float2 ev = *(const float2*)&eattr2[2 * e];
    e0 = ev.x; e1 = ev.y;
  } else {
    s = d = e - E;
    e0 = nd4[4 * s + 1]; e1 = nd4[4 * s + 2];
  }
  float4 As = *(const float4*)&asd[4 * s];
  float4 Ad = *(const float4*)&asd[4 * d];
  float x0 = As.x + Ad.z + e0 * we[0] + e1 * we[1];
  float x1 = As.y + Ad.w + e0 * we[2] + e1 * we[3];
  x0 = x0 >= 0.f ? x0 : 0.2f * x0;
  x1 = x1 >= 0.f ? x1 : 0.2f * x1;
  float ea0 = expf(x0), ea1 = expf(x1);
  *(float2*)&ea[2 * e] = make_float2(ea0, ea1);
  atomicAdd(&denom[2 * d], ea0);
  atomicAdd(&denom[2 * d + 1], ea1);
}

// edge aggregation (wave/edge): agg[d,c] += 0.5*(alpha0*h[s,0,c] + alpha1*h[s,1,c])
__global__ void k_edge3(const int* __restrict__ src, const int* __restrict__ dst,
                        const float* __restrict__ ea, const float* __restrict__ denom,
                        const float* __restrict__ h, float* __restrict__ agg, int E, int N) {
  long long idx = (long long)blockIdx.x * blockDim.x + threadIdx.x;
  int e = (int)(idx >> 6), lane = (int)(idx & 63);
  if (e >= E + N) return;
  int s, d;
  if (e < E) { s = src[e]; d = dst[e]; } else { s = d = e - E; }
  float al0 = ea[2 * e]     / (denom[2 * d]     + 1e-16f);
  float al1 = ea[2 * e + 1] / (denom[2 * d + 1] + 1e-16f);
  float v = 0.5f * (al0 * h[(long long)s * 128 + lane] + al1 * h[(long long)s * 128 + 64 + lane]);
  atomicAdd(&agg[(long long)d * 64 + lane], v);
}

template<bool RELU>
__global__ void k_bias_act(const float* __restrict__ in, const float* __restrict__ b,
                           float* __restrict__ o, int total) {
  int i = blockIdx.x * blockDim.x + threadIdx.x;
  if (i >= total) return;
  float v = in[i] + b[i & 63];
  if (RELU) v = fmaxf(v, 0.f);
  o[i] = v;
}

// per-node heads: p_n = softmax(h@Wn + bn); r = h@Wec (bec added per-edge). One wave/node.
__global__ void k_head(const float* __restrict__ hh, const float* __restrict__ Wn,
                       const float* __restrict__ bn, const float* __restrict__ Wec,
                       float* __restrict__ p_n, float* __restrict__ r, int N) {
  int idx = blockIdx.x * blockDim.x + threadIdx.x;
  int n = idx >> 6, lane = idx & 63;
  if (n >= N) return;
  float v = hh[(long long)n * 64 + lane];
  float p[7];
#pragma unroll
  for (int j = 0; j < 5; ++j) p[j] = v * Wn[lane * 5 + j];
  p[5] = v * Wec[lane * 2];
  p[6] = v * Wec[lane * 2 + 1];
  for (int off = 32; off; off >>= 1) {
#pragma unroll
    for (int j = 0; j < 7; ++j) p[j] += __shfl_down(p[j], off);
  }
  if (lane == 0) {
    float l[5]; float m = -1e30f;
#pragma unroll
    for (int j = 0; j < 5; ++j) { l[j] = p[j] + bn[j]; m = fmaxf(m, l[j]); }
    float ssum = 0.f;
#pragma unroll
    for (int j = 0; j < 5; ++j) { l[j] = expf(l[j] - m); ssum += l[j]; }
    float inv = 1.0f / ssum;
#pragma unroll
    for (int j = 0; j < 5; ++j) p_n[5 * n + j] = l[j] * inv;
    r[2 * n] = p[5];
    r[2 * n + 1] = p[6];
  }
}

// factor-graph edge update (+ eab scatter). FIRST: build p_e from logits. LAST: emit log.
template<bool FIRST, bool LAST>
__global__ void k_fg_edge(const int* __restrict__ src, const int* __restrict__ dst,
                          const float* __restrict__ r, const float* __restrict__ bec,
                          const float* __restrict__ p_n, float* __restrict__ p_e,
                          float* __restrict__ s_acc, const float* __restrict__ consts,
                          float* __restrict__ out_e, int E) {
  int e = blockIdx.x * blockDim.x + threadIdx.x;
  if (e >= E) return;
  int s = src[e], d = dst[e];
  float pe0, pe1;
  if (FIRST) {
    float l0 = 0.5f * (r[2 * s] + r[2 * d]) + bec[0];
    float l1 = 0.5f * (r[2 * s + 1] + r[2 * d + 1]) + bec[1];
    float m = fmaxf(l0, l1);
    float x0 = expf(l0 - m), x1 = expf(l1 - m);
    float inv = 1.0f / (x0 + x1);
    pe0 = x0 * inv; pe1 = x1 * inv;
  } else {
    pe0 = p_e[2 * e]; pe1 = p_e[2 * e + 1];
  }
  float nab_s = 1.0f - p_n[5 * s];
  float nab_d = 1.0f - p_n[5 * d];
  float ena = fmaxf(nab_s, nab_d);
  float f = 1.0f + ena * consts[8];           // GAMMA = 1
  pe1 *= f;
  float inv2 = 1.0f / (pe0 + pe1);
  pe0 *= inv2; pe1 *= inv2;
  if (LAST) {
    out_e[2 * e] = logf(pe0 + 1e-9f);
    out_e[2 * e + 1] = logf(pe1 + 1e-9f);
  } else {
    *(float2*)&p_e[2 * e] = make_float2(pe0, pe1);
  }
  float eab = pe1;                            // 1 - pe0
  atomicAdd(&s_acc[s], eab);
  atomicAdd(&s_acc[d], eab);
}

template<bool LAST>
__global__ void k_fg_node(float* __restrict__ p_n, const float* __restrict__ s_acc,
                          const float* __restrict__ deg_fg, const float* __restrict__ consts,
                          float* __restrict__ out_n, int N) {
  int n = blockIdx.x * blockDim.x + threadIdx.x;
  if (n >= N) return;
  float mean = s_acc[n] / (deg_fg[n] + 1e-6f);
  float f = 1.0f + mean * consts[9];          // GAMMA = 1
  float p0 = p_n[5 * n];
  float p1 = p_n[5 * n + 1] * f;
  float p2 = p_n[5 * n + 2] * f;
  float p3 = p_n[5 * n + 3] * f;
  float p4 = p_n[5 * n + 4] * f;
  float inv = 1.0f / (p0 + p1 + p2 + p3 + p4);
  p0 *= inv; p1 *= inv; p2 *= inv; p3 *= inv; p4 *= inv;
  if (LAST) {
    out_n[5 * n]     = logf(p0 + 1e-9f);
    out_n[5 * n + 1] = logf(p1 + 1e-9f);
    out_n[5 * n + 2] = logf(p2 + 1e-9f);
    out_n[5 * n + 3] = logf(p3 + 1e-9f);
    out_n[5 * n + 4] = logf(p4 + 1e-9f);
  } else {
    p_n[5 * n]     = p0;
    p_n[5 * n + 1] = p1;
    p_n[5 * n + 2] = p2;
    p_n[5 * n + 3] = p3;
    p_n[5 * n + 4] = p4;
  }
}

extern "C" void kernel_launch(void* const* d_in, const int* in_sizes, int n_in,
                              void* d_out, int out_size, void* d_ws, size_t ws_size,
                              hipStream_t stream) {
  const float* x      = (const float*)d_in[0];
  const int*   ei     = (const int*)d_in[1];
  const float* eattr  = (const float*)d_in[2];
  const float* W1     = (const float*)d_in[3];
  const float* atts1  = (const float*)d_in[4];
  const float* attd1  = (const float*)d_in[5];
  const float* We1    = (const float*)d_in[6];
  const float* atte1  = (const float*)d_in[7];
  const float* b1     = (const float*)d_in[8];
  const float* W2     = (const float*)d_in[9];
  const float* atts2  = (const float*)d_in[10];
  const float* attd2  = (const float*)d_in[11];
  const float* We2    = (const float*)d_in[12];
  const float* atte2  = (const float*)d_in[13];
  const float* b2     = (const float*)d_in[14];
  const float* Wn     = (const float*)d_in[15];
  const float* bn     = (const float*)d_in[16];
  const float* Wec    = (const float*)d_in[17];
  const float* bec    = (const float*)d_in[18];
  const float* nodefw = (const float*)d_in[19];
  const float* edgefw = (const float*)d_in[20];

  const int N = in_sizes[0] / 128;
  const int E = in_sizes[1] / 2;
  const int EL = E + N;  // edges incl. self-loops
  const int* src = ei;
  const int* dst = ei + E;

  float* out_n = (float*)d_out;
  float* out_e = out_n + (long long)N * 5;

  // ---- workspace carve (f32) ----
  size_t off = 0;
  float* base = (float*)d_ws;
  auto carve = [&](size_t nelem) { float* p = base + off; off += (nelem + 3) & ~(size_t)3; return p; };
  float* h         = carve((size_t)N * 128);
  float* x2        = carve((size_t)N * 64);   // relu(out1)+b1; later reused as out2
  float* agg       = carve((size_t)N * 64);
  float* asd       = carve((size_t)N * 4);    // {as0,as1,ad0,ad1}
  float* denom     = carve((size_t)N * 2);
  float* nd4       = carve((size_t)N * 4);    // {deg_dst, loop0, loop1, _}
  float* deg_src   = carve((size_t)N);
  float* deg_fg    = carve((size_t)N);
  float* a_ea      = carve((size_t)EL * 2);
  float* p_n       = carve((size_t)N * 5);
  float* r         = carve((size_t)N * 2);
  float* p_e       = carve((size_t)E * 2);
  float* s_acc     = carve((size_t)N);
  float* consts    = carve(16);
  if (off * sizeof(float) > ws_size) return;  // insufficient scratch: fail loudly

  const int B = 256;
  const int gE  = cdiv_i(E, B);
  const int gEL = cdiv_i(EL, B);
  const int gN  = cdiv_i(N, B);
  const int gNW = cdiv_i((long long)N * 64, B);   // wave-per-node kernels
  const int gELW = cdiv_i((long long)EL * 64, B); // wave-per-edge kernels
  const int gNC = cdiv_i((long long)N * 64, B);

  // ---- graph-invariant prep ----
  hipMemsetAsync(nd4, 0, (size_t)N * 16, stream);
  hipMemsetAsync(deg_src, 0, (size_t)N * 4, stream);
  k_prep_consts<<<1, 64, 0, stream>>>(We1, atte1, We2, atte2, nodefw, edgefw, consts);
  k_degrees<<<gE, B, 0, stream>>>(src, dst, eattr, nd4, deg_src, E);
  k_loop_fin<<<gN, B, 0, stream>>>(nd4, deg_src, deg_fg, N);

  // ---- GAT layer 1 ----
  k_gemm<128><<<cdiv_i(N, 32), 256, 0, stream>>>(x, W1, h, N);
  k_att_nodes<<<gNW, B, 0, stream>>>(h, atts1, attd1, asd, N);
  hipMemsetAsync(denom, 0, (size_t)N * 8, stream);
  hipMemsetAsync(agg, 0, (size_t)N * 64 * 4, stream);
  k_edge12<<<gEL, B, 0, stream>>>(src, dst, eattr, nd4, asd, consts, a_ea, denom, E, N);
  k_edge3<<<gELW, B, 0, stream>>>(src, dst, a_ea, denom, h, agg, E, N);
  k_bias_act<true><<<gNC, B, 0, stream>>>(agg, b1, x2, N * 64);

  // ---- GAT layer 2 ----
  k_gemm<64><<<cdiv_i(N, 32), 256, 0, stream>>>(x2, W2, h, N);
  k_att_nodes<<<gNW, B, 0, stream>>>(h, atts2, attd2, asd, N);
  hipMemsetAsync(denom, 0, (size_t)N * 8, stream);
  hipMemsetAsync(agg, 0, (size_t)N * 64 * 4, stream);
  k_edge12<<<gEL, B, 0, stream>>>(src, dst, eattr, nd4, asd, consts + 4, a_ea, denom, E, N);
  k_edge3<<<gELW, B, 0, stream>>>(src, dst, a_ea, denom, h, agg, E, N);
  k_bias_act<false><<<gNC, B, 0, stream>>>(agg, b2, x2, N * 64);  // x2 now = final node emb

  // ---- heads ----
  k_head<<<gNW, B, 0, stream>>>(x2, Wn, bn, Wec, p_n, r, N);

  // ---- factor graph, 2 iterations ----
  hipMemsetAsync(s_acc, 0, (size_t)N * 4, stream);
  k_fg_edge<true, false><<<gE, B, 0, stream>>>(src, dst, r, bec, p_n, p_e, s_acc, consts, nullptr, E);
  k_fg_node<false><<<gN, B, 0, stream>>>(p_n, s_acc, deg_fg, consts, nullptr, N);
  hipMemsetAsync(s_acc, 0, (size_t)N * 4, stream);
  k_fg_edge<false, true><<<gE, B, 0, stream>>>(src, dst, r, bec, p_n, p_e, s_acc, consts, out_e, E);
  k_fg_node<true><<<gN, B, 0, stream>>>(p_n, s_acc, deg_fg, consts, out_n, N);
}

// Round 3
// 616.182 us; speedup vs baseline: 2.0830x; 1.7844x over previous
//
#include <hip/hip_runtime.h>
#include <math.h>

// GraphRespiratory: 2-layer GAT (edge features, concat=False) + factor graph.
// N=50000, E=800000, IN=128, HID=OUT=64, H=2, NC=5, EC=2, NUM_ITER=2, GAMMA=1.
//
// R2 changes vs R1:
//  - Build dst-sorted CSR once (int histogram + block scan + cursor scatter).
//  - k_gat_pull: one wave per dst node fuses edge-logit+exp+denom+aggregate+
//    bias+act. No atomics, no agg/denom/a_ea buffers, no memsets for them.
//    Self-loop attr (per-dst eattr mean) computed in-wave via reduction.
//  - fg node state packed: fgn[n]={r0,r1,pn0,_} -> 1 gather line per endpoint.

static inline int cdiv_i(long long a, long long b) { return (int)((a + b - 1) / b); }

// consts: [0..3] w_e1[h][k], [4..7] w_e2[h][k], [8] avg_ef, [9] avg_nf
__global__ void k_prep_consts(const float* __restrict__ We1, const float* __restrict__ att_e1,
                              const float* __restrict__ We2, const float* __restrict__ att_e2,
                              const float* __restrict__ node_fw, const float* __restrict__ edge_fw,
                              float* __restrict__ consts) {
  if (blockIdx.x != 0 || threadIdx.x != 0) return;
  for (int h = 0; h < 2; ++h) {
    for (int k = 0; k < 2; ++k) {
      float s1 = 0.f, s2 = 0.f;
      for (int c = 0; c < 64; ++c) {
        s1 += We1[k * 128 + h * 64 + c] * att_e1[h * 64 + c];
        s2 += We2[k * 128 + h * 64 + c] * att_e2[h * 64 + c];
      }
      consts[h * 2 + k] = s1;
      consts[4 + h * 2 + k] = s2;
    }
  }
  float ef = 0.f;                      // edge_fw is [EC=2, NC=5]; mean of [1:,1:]
  for (int j = 1; j < 5; ++j) ef += edge_fw[5 + j];
  consts[8] = ef * 0.25f;
  float nf = 0.f;                      // node_fw is [NC=5, EC=2]; mean of [1:,1:]
  for (int i = 1; i < 5; ++i) nf += node_fw[i * 2 + 1];
  consts[9] = nf * 0.25f;
}

// int degree histograms (2 atomic lines per edge)
__global__ void k_degrees(const int* __restrict__ src, const int* __restrict__ dst,
                          int* __restrict__ deg_dst, int* __restrict__ deg_src, int E) {
  int e = blockIdx.x * blockDim.x + threadIdx.x;
  if (e >= E) return;
  atomicAdd(&deg_dst[dst[e]], 1);
  atomicAdd(&deg_src[src[e]], 1);
}

__global__ void k_deg_fg(const int* __restrict__ deg_dst, const int* __restrict__ deg_src,
                         float* __restrict__ deg_fg, int N) {
  int n = blockIdx.x * blockDim.x + threadIdx.x;
  if (n >= N) return;
  deg_fg[n] = (float)(deg_dst[n] + deg_src[n]);
}

// ---- 3-kernel exclusive scan of deg_dst -> rowptr (N=50000, 196 blocks) ----
__global__ void k_scan_partial(const int* __restrict__ deg, int* __restrict__ part, int N) {
  __shared__ int l[256];
  int n = blockIdx.x * 256 + threadIdx.x;
  int v = (n < N) ? deg[n] : 0;
  l[threadIdx.x] = v; __syncthreads();
  for (int s = 128; s; s >>= 1) { if (threadIdx.x < s) l[threadIdx.x] += l[threadIdx.x + s]; __syncthreads(); }
  if (threadIdx.x == 0) part[blockIdx.x] = l[0];
}
__global__ void k_scan_root(int* __restrict__ part, int P) {
  __shared__ int l[256];
  int t = threadIdx.x;
  int v = (t < P) ? part[t] : 0;
  l[t] = v; __syncthreads();
  for (int off = 1; off < 256; off <<= 1) {
    int x = (t >= off) ? l[t - off] : 0; __syncthreads();
    l[t] += x; __syncthreads();
  }
  if (t < P) part[t] = l[t] - v;  // exclusive
}
__global__ void k_scan_final(const int* __restrict__ deg, const int* __restrict__ part,
                             int* __restrict__ rowptr, int* __restrict__ cursor, int N) {
  __shared__ int l[256];
  int t = threadIdx.x, n = blockIdx.x * 256 + t;
  int v = (n < N) ? deg[n] : 0;
  l[t] = v; __syncthreads();
  for (int off = 1; off < 256; off <<= 1) {
    int x = (t >= off) ? l[t - off] : 0; __syncthreads();
    l[t] += x; __syncthreads();
  }
  if (n < N) { int rp = part[blockIdx.x] + l[t] - v; rowptr[n] = rp; cursor[n] = rp; }
}

// scatter packed edge records into dst-sorted CSR: rec = {src(int bits), e0, e1, _}
__global__ void k_csr_scatter(const int* __restrict__ src, const int* __restrict__ dst,
                              const float* __restrict__ eattr2, int* __restrict__ cursor,
                              float4* __restrict__ rec, int E) {
  int e = blockIdx.x * blockDim.x + threadIdx.x;
  if (e >= E) return;
  int d = dst[e];
  int pos = atomicAdd(&cursor[d], 1);
  float2 ev = *(const float2*)&eattr2[2 * e];
  float4 r;
  r.x = __int_as_float(src[e]); r.y = ev.x; r.z = ev.y; r.w = 0.f;
  rec[pos] = r;
}

// C[N,128] = A[N,K] @ W[K,128], f32. W fully staged in LDS, 32 rows/block.
template<int K>
__global__ __launch_bounds__(256)
void k_gemm(const float* __restrict__ A, const float* __restrict__ W,
            float* __restrict__ C, int N) {
  __shared__ float Wl[K * 128];
  __shared__ float Al[32 * K];
  int tid = threadIdx.x;
  for (int i = tid * 4; i < K * 128; i += 256 * 4)
    *(float4*)&Wl[i] = *(const float4*)&W[i];
  int row0 = blockIdx.x * 32;
  for (int i = tid * 4; i < 32 * K; i += 256 * 4) {
    int r = i / K, c = i % K;
    int gr = row0 + r;
    float4 v = make_float4(0.f, 0.f, 0.f, 0.f);
    if (gr < N) v = *(const float4*)&A[(long long)gr * K + c];
    *(float4*)&Al[r * K + c] = v;
  }
  __syncthreads();
  int col = tid & 127;
  int rbase = (tid >> 7) * 16;
  float acc[16];
#pragma unroll
  for (int r = 0; r < 16; ++r) acc[r] = 0.f;
  for (int k = 0; k < K; ++k) {
    float w = Wl[k * 128 + col];
#pragma unroll
    for (int r = 0; r < 16; ++r) acc[r] += Al[(rbase + r) * K + k] * w;
  }
#pragma unroll
  for (int r = 0; r < 16; ++r) {
    int gr = row0 + rbase + r;
    if (gr < N) C[(long long)gr * 128 + col] = acc[r];
  }
}

// per-node attention scalars packed: asd[n] = {as0, as1, ad0, ad1}. One wave/node.
__global__ void k_att_nodes(const float* __restrict__ h,
                            const float* __restrict__ atts, const float* __restrict__ attd,
                            float* __restrict__ asd, int N) {
  int idx = blockIdx.x * blockDim.x + threadIdx.x;
  int n = idx >> 6, lane = idx & 63;
  if (n >= N) return;
  float v0 = h[(long long)n * 128 + lane];
  float v1 = h[(long long)n * 128 + 64 + lane];
  float ps0 = v0 * atts[lane];
  float ps1 = v1 * atts[64 + lane];
  float pd0 = v0 * attd[lane];
  float pd1 = v1 * attd[64 + lane];
  for (int off = 32; off; off >>= 1) {
    ps0 += __shfl_down(ps0, off);
    ps1 += __shfl_down(ps1, off);
    pd0 += __shfl_down(pd0, off);
    pd1 += __shfl_down(pd1, off);
  }
  if (lane == 0) {
    asd[4 * n] = ps0; asd[4 * n + 1] = ps1;
    asd[4 * n + 2] = pd0; asd[4 * n + 3] = pd1;
  }
}

// Fused GAT edge phase, pull-mode. One wave per dst node.
// Phase A (lanes = edges): ea = exp(leaky(as[s]+ad[d]+we·eattr)); wave-reduce
// denom and eattr sums (for the self-loop mean). Phase B: shfl-broadcast each
// edge, all 64 lanes accumulate ea*h[src]. Epilogue: self-loop, /denom, bias, act.
template<bool RELU>
__global__ __launch_bounds__(256)
void k_gat_pull(const int* __restrict__ rowptr, const float4* __restrict__ rec,
                const float* __restrict__ asd, const float* __restrict__ h,
                const float* __restrict__ we, const float* __restrict__ bias,
                float* __restrict__ out, int N, int E) {
  int wv = threadIdx.x >> 6, lane = threadIdx.x & 63;
  int d = blockIdx.x * 4 + wv;
  if (d >= N) return;
  int r0 = rowptr[d];
  int r1 = (d + 1 < N) ? rowptr[d + 1] : E;
  int deg = r1 - r0;
  float4 Ad = *(const float4*)&asd[4 * d];
  float w0 = we[0], w1 = we[1], w2 = we[2], w3 = we[3];
  float den0 = 0.f, den1 = 0.f, acc0 = 0.f, acc1 = 0.f, se0 = 0.f, se1 = 0.f;
  for (int cb = 0; cb < deg; cb += 64) {
    int j = cb + lane;
    int s = 0; float ea0 = 0.f, ea1 = 0.f, e0 = 0.f, e1 = 0.f;
    if (j < deg) {
      float4 rc = rec[r0 + j];
      s = __float_as_int(rc.x); e0 = rc.y; e1 = rc.z;
      float4 As = *(const float4*)&asd[4 * s];
      float x0 = As.x + Ad.z + e0 * w0 + e1 * w1;
      float x1 = As.y + Ad.w + e0 * w2 + e1 * w3;
      x0 = x0 >= 0.f ? x0 : 0.2f * x0;
      x1 = x1 >= 0.f ? x1 : 0.2f * x1;
      ea0 = expf(x0); ea1 = expf(x1);
    }
    float t0 = ea0, t1 = ea1, t2 = e0, t3 = e1;
    for (int off = 32; off; off >>= 1) {
      t0 += __shfl_xor(t0, off); t1 += __shfl_xor(t1, off);
      t2 += __shfl_xor(t2, off); t3 += __shfl_xor(t3, off);
    }
    den0 += t0; den1 += t1; se0 += t2; se1 += t3;
    int m = min(64, deg - cb);
    for (int j2 = 0; j2 < m; ++j2) {
      int sj = __shfl(s, j2);
      float a0 = __shfl(ea0, j2);
      float a1 = __shfl(ea1, j2);
      const float* hp = &h[(long long)sj * 128 + lane];
      acc0 += a0 * hp[0];
      acc1 += a1 * hp[64];
    }
  }
  // self-loop: edge_attr = mean of incident (by dst) eattr
  float id = 1.0f / fmaxf((float)deg, 1.0f);
  float le0 = se0 * id, le1 = se1 * id;
  float x0 = Ad.x + Ad.z + le0 * w0 + le1 * w1;
  float x1 = Ad.y + Ad.w + le0 * w2 + le1 * w3;
  x0 = x0 >= 0.f ? x0 : 0.2f * x0;
  x1 = x1 >= 0.f ? x1 : 0.2f * x1;
  float eas0 = expf(x0), eas1 = expf(x1);
  den0 += eas0; den1 += eas1;
  const float* hd = &h[(long long)d * 128 + lane];
  acc0 += eas0 * hd[0];
  acc1 += eas1 * hd[64];
  float v = 0.5f * (acc0 / (den0 + 1e-16f) + acc1 / (den1 + 1e-16f)) + bias[lane];
  if (RELU) v = fmaxf(v, 0.f);
  out[(long long)d * 64 + lane] = v;
}

// per-node heads: p_n = softmax(h@Wn + bn); fgn = {r0, r1, p_n[0], _}. One wave/node.
__global__ void k_head(const float* __restrict__ hh, const float* __restrict__ Wn,
                       const float* __restrict__ bn, const float* __restrict__ Wec,
                       float* __restrict__ p_n, float* __restrict__ fgn, int N) {
  int idx = blockIdx.x * blockDim.x + threadIdx.x;
  int n = idx >> 6, lane = idx & 63;
  if (n >= N) return;
  float v = hh[(long long)n * 64 + lane];
  float p[7];
#pragma unroll
  for (int j = 0; j < 5; ++j) p[j] = v * Wn[lane * 5 + j];
  p[5] = v * Wec[lane * 2];
  p[6] = v * Wec[lane * 2 + 1];
  for (int off = 32; off; off >>= 1) {
#pragma unroll
    for (int j = 0; j < 7; ++j) p[j] += __shfl_down(p[j], off);
  }
  if (lane == 0) {
    float l[5]; float m = -1e30f;
#pragma unroll
    for (int j = 0; j < 5; ++j) { l[j] = p[j] + bn[j]; m = fmaxf(m, l[j]); }
    float ssum = 0.f;
#pragma unroll
    for (int j = 0; j < 5; ++j) { l[j] = expf(l[j] - m); ssum += l[j]; }
    float inv = 1.0f / ssum;
#pragma unroll
    for (int j = 0; j < 5; ++j) p_n[5 * n + j] = l[j] * inv;
    fgn[4 * n] = p[5];
    fgn[4 * n + 1] = p[6];
    fgn[4 * n + 2] = l[0] * inv;   // p_n[:,0]
    fgn[4 * n + 3] = 0.f;
  }
}

// factor-graph edge update (+ eab scatter). FIRST: build p_e from logits. LAST: emit log.
// fgn[n] = {r0, r1, pn0, _} -> one gather line per endpoint.
template<bool FIRST, bool LAST>
__global__ void k_fg_edge(const int* __restrict__ src, const int* __restrict__ dst,
                          const float* __restrict__ fgn, const float* __restrict__ bec,
                          float* __restrict__ p_e, float* __restrict__ s_acc,
                          const float* __restrict__ consts, float* __restrict__ out_e, int E) {
  int e = blockIdx.x * blockDim.x + threadIdx.x;
  if (e >= E) return;
  int s = src[e], d = dst[e];
  float4 Fs = *(const float4*)&fgn[4 * s];
  float4 Fd = *(const float4*)&fgn[4 * d];
  float pe0, pe1;
  if (FIRST) {
    float l0 = 0.5f * (Fs.x + Fd.x) + bec[0];
    float l1 = 0.5f * (Fs.y + Fd.y) + bec[1];
    float m = fmaxf(l0, l1);
    float x0 = expf(l0 - m), x1 = expf(l1 - m);
    float inv = 1.0f / (x0 + x1);
    pe0 = x0 * inv; pe1 = x1 * inv;
  } else {
    float2 pv = *(const float2*)&p_e[2 * e];
    pe0 = pv.x; pe1 = pv.y;
  }
  float ena = fmaxf(1.0f - Fs.z, 1.0f - Fd.z);
  float f = 1.0f + ena * consts[8];           // GAMMA = 1
  pe1 *= f;
  float inv2 = 1.0f / (pe0 + pe1);
  pe0 *= inv2; pe1 *= inv2;
  if (LAST) {
    out_e[2 * e] = logf(pe0 + 1e-9f);
    out_e[2 * e + 1] = logf(pe1 + 1e-9f);
  } else {
    *(float2*)&p_e[2 * e] = make_float2(pe0, pe1);
  }
  float eab = pe1;                            // 1 - pe0
  atomicAdd(&s_acc[s], eab);
  atomicAdd(&s_acc[d], eab);
}

template<bool LAST>
__global__ void k_fg_node(float* __restrict__ p_n, float* __restrict__ fgn,
                          const float* __restrict__ s_acc, const float* __restrict__ deg_fg,
                          const float* __restrict__ consts, float* __restrict__ out_n, int N) {
  int n = blockIdx.x * blockDim.x + threadIdx.x;
  if (n >= N) return;
  float mean = s_acc[n] / (deg_fg[n] + 1e-6f);
  float f = 1.0f + mean * consts[9];          // GAMMA = 1
  float p0 = p_n[5 * n];
  float p1 = p_n[5 * n + 1] * f;
  float p2 = p_n[5 * n + 2] * f;
  float p3 = p_n[5 * n + 3] * f;
  float p4 = p_n[5 * n + 4] * f;
  float inv = 1.0f / (p0 + p1 + p2 + p3 + p4);
  p0 *= inv; p1 *= inv; p2 *= inv; p3 *= inv; p4 *= inv;
  if (LAST) {
    out_n[5 * n]     = logf(p0 + 1e-9f);
    out_n[5 * n + 1] = logf(p1 + 1e-9f);
    out_n[5 * n + 2] = logf(p2 + 1e-9f);
    out_n[5 * n + 3] = logf(p3 + 1e-9f);
    out_n[5 * n + 4] = logf(p4 + 1e-9f);
  } else {
    p_n[5 * n]     = p0;
    p_n[5 * n + 1] = p1;
    p_n[5 * n + 2] = p2;
    p_n[5 * n + 3] = p3;
    p_n[5 * n + 4] = p4;
    fgn[4 * n + 2] = p0;   // keep packed state in sync for next fg_edge
  }
}

extern "C" void kernel_launch(void* const* d_in, const int* in_sizes, int n_in,
                              void* d_out, int out_size, void* d_ws, size_t ws_size,
                              hipStream_t stream) {
  const float* x      = (const float*)d_in[0];
  const int*   ei     = (const int*)d_in[1];
  const float* eattr  = (const float*)d_in[2];
  const float* W1     = (const float*)d_in[3];
  const float* atts1  = (const float*)d_in[4];
  const float* attd1  = (const float*)d_in[5];
  const float* We1    = (const float*)d_in[6];
  const float* atte1  = (const float*)d_in[7];
  const float* b1     = (const float*)d_in[8];
  const float* W2     = (const float*)d_in[9];
  const float* atts2  = (const float*)d_in[10];
  const float* attd2  = (const float*)d_in[11];
  const float* We2    = (const float*)d_in[12];
  const float* atte2  = (const float*)d_in[13];
  const float* b2     = (const float*)d_in[14];
  const float* Wn     = (const float*)d_in[15];
  const float* bn     = (const float*)d_in[16];
  const float* Wec    = (const float*)d_in[17];
  const float* bec    = (const float*)d_in[18];
  const float* nodefw = (const float*)d_in[19];
  const float* edgefw = (const float*)d_in[20];

  const int N = in_sizes[0] / 128;
  const int E = in_sizes[1] / 2;
  const int* src = ei;
  const int* dst = ei + E;

  float* out_n = (float*)d_out;
  float* out_e = out_n + (long long)N * 5;

  // ---- workspace carve (f32 units, 16B aligned) ----
  size_t off = 0;
  float* base = (float*)d_ws;
  auto carve = [&](size_t nelem) { float* p = base + off; off += (nelem + 3) & ~(size_t)3; return p; };
  float* h        = carve((size_t)N * 128);
  float* x2       = carve((size_t)N * 64);
  float* asd      = carve((size_t)N * 4);
  float* rec      = carve((size_t)E * 4);     // float4 CSR records
  int*   deg_dst  = (int*)carve((size_t)N);
  int*   deg_src  = (int*)carve((size_t)N);
  int*   rowptr   = (int*)carve((size_t)N);
  int*   cursor   = (int*)carve((size_t)N);
  int*   part     = (int*)carve(256);
  float* deg_fg   = carve((size_t)N);
  float* p_n      = carve((size_t)N * 5);
  float* fgn      = carve((size_t)N * 4);
  float* p_e      = carve((size_t)E * 2);
  float* s_acc    = carve((size_t)N);
  float* consts   = carve(16);
  if (off * sizeof(float) > ws_size) return;  // insufficient scratch: fail loudly

  const int B = 256;
  const int gE  = cdiv_i(E, B);
  const int gN  = cdiv_i(N, B);
  const int gNW = cdiv_i((long long)N * 64, B);   // wave-per-node kernels
  const int P   = cdiv_i(N, 256);                 // scan partials (196)

  // ---- graph prep: degrees + CSR ----
  hipMemsetAsync(deg_dst, 0, (size_t)N * 4, stream);
  hipMemsetAsync(deg_src, 0, (size_t)N * 4, stream);
  k_prep_consts<<<1, 64, 0, stream>>>(We1, atte1, We2, atte2, nodefw, edgefw, consts);
  k_degrees<<<gE, B, 0, stream>>>(src, dst, deg_dst, deg_src, E);
  k_deg_fg<<<gN, B, 0, stream>>>(deg_dst, deg_src, deg_fg, N);
  k_scan_partial<<<P, 256, 0, stream>>>(deg_dst, part, N);
  k_scan_root<<<1, 256, 0, stream>>>(part, P);
  k_scan_final<<<P, 256, 0, stream>>>(deg_dst, part, rowptr, cursor, N);
  k_csr_scatter<<<gE, B, 0, stream>>>(src, dst, eattr, cursor, (float4*)rec, E);

  // ---- GAT layer 1 ----
  k_gemm<128><<<cdiv_i(N, 32), 256, 0, stream>>>(x, W1, h, N);
  k_att_nodes<<<gNW, B, 0, stream>>>(h, atts1, attd1, asd, N);
  k_gat_pull<true><<<cdiv_i(N, 4), 256, 0, stream>>>(rowptr, (const float4*)rec, asd, h,
                                                     consts, b1, x2, N, E);

  // ---- GAT layer 2 ----
  k_gemm<64><<<cdiv_i(N, 32), 256, 0, stream>>>(x2, W2, h, N);
  k_att_nodes<<<gNW, B, 0, stream>>>(h, atts2, attd2, asd, N);
  k_gat_pull<false><<<cdiv_i(N, 4), 256, 0, stream>>>(rowptr, (const float4*)rec, asd, h,
                                                      consts + 4, b2, x2, N, E);

  // ---- heads ----
  k_head<<<gNW, B, 0, stream>>>(x2, Wn, bn, Wec, p_n, fgn, N);

  // ---- factor graph, 2 iterations ----
  hipMemsetAsync(s_acc, 0, (size_t)N * 4, stream);
  k_fg_edge<true, false><<<gE, B, 0, stream>>>(src, dst, fgn, bec, p_e, s_acc, consts, nullptr, E);
  k_fg_node<false><<<gN, B, 0, stream>>>(p_n, fgn, s_acc, deg_fg, consts, nullptr, N);
  hipMemsetAsync(s_acc, 0, (size_t)N * 4, stream);
  k_fg_edge<false, true><<<gE, B, 0, stream>>>(src, dst, fgn, bec, p_e, s_acc, consts, out_e, E);
  k_fg_node<true><<<gN, B, 0, stream>>>(p_n, fgn, s_acc, deg_fg, consts, out_n, N);
}

// Round 4
// 591.556 us; speedup vs baseline: 2.1697x; 1.0416x over previous
//
#include <hip/hip_runtime.h>
#include <math.h>

// GraphRespiratory: 2-layer GAT (edge features, concat=False) + factor graph.
// N=50000, E=800000, IN=128, HID=OUT=64, H=2, NC=5, EC=2, NUM_ITER=2, GAMMA=1.
//
// R3 changes vs R2:
//  - Factor graph fully pull-mode: p_e tracked as odds (never stored), fg state
//    packed fgn[n]={q=r1-r0, nab0, nab1, _}. Per-iteration: ONE node-pull kernel
//    (gathers fgn[other] via dst-CSR + new src-CSR, recomputes edge chain,
//    accumulates eab, updates p_n). Zero scattered atomics per iteration.
//    Final coalesced edge pass emits out_e. p_e/s_acc buffers + k_fg_node gone.
//  - src-CSR (neighbor id, 4B) built inside k_csr_scatter (shares src/dst reads).
//  - h stored interleaved [N][64][2]: gat_pull inner loop = one 8B load/lane.

static inline int cdiv_i(long long a, long long b) { return (int)((a + b - 1) / b); }

// consts: [0..3] w_e1[h][k], [4..7] w_e2[h][k], [8] avg_ef, [9] avg_nf, [10] dbec
__global__ void k_prep_consts(const float* __restrict__ We1, const float* __restrict__ att_e1,
                              const float* __restrict__ We2, const float* __restrict__ att_e2,
                              const float* __restrict__ node_fw, const float* __restrict__ edge_fw,
                              const float* __restrict__ bec, float* __restrict__ consts) {
  if (blockIdx.x != 0 || threadIdx.x != 0) return;
  for (int h = 0; h < 2; ++h) {
    for (int k = 0; k < 2; ++k) {
      float s1 = 0.f, s2 = 0.f;
      for (int c = 0; c < 64; ++c) {
        s1 += We1[k * 128 + h * 64 + c] * att_e1[h * 64 + c];
        s2 += We2[k * 128 + h * 64 + c] * att_e2[h * 64 + c];
      }
      consts[h * 2 + k] = s1;
      consts[4 + h * 2 + k] = s2;
    }
  }
  float ef = 0.f;                      // edge_fw is [EC=2, NC=5]; mean of [1:,1:]
  for (int j = 1; j < 5; ++j) ef += edge_fw[5 + j];
  consts[8] = ef * 0.25f;
  float nf = 0.f;                      // node_fw is [NC=5, EC=2]; mean of [1:,1:]
  for (int i = 1; i < 5; ++i) nf += node_fw[i * 2 + 1];
  consts[9] = nf * 0.25f;
  consts[10] = bec[1] - bec[0];
}

// int degree histograms
__global__ void k_degrees(const int* __restrict__ src, const int* __restrict__ dst,
                          int* __restrict__ deg_dst, int* __restrict__ deg_src, int E) {
  int e = blockIdx.x * blockDim.x + threadIdx.x;
  if (e >= E) return;
  atomicAdd(&deg_dst[dst[e]], 1);
  atomicAdd(&deg_src[src[e]], 1);
}

// ---- 3-kernel exclusive scan of deg -> rowptr (N=50000, 196 blocks) ----
__global__ void k_scan_partial(const int* __restrict__ deg, int* __restrict__ part, int N) {
  __shared__ int l[256];
  int n = blockIdx.x * 256 + threadIdx.x;
  int v = (n < N) ? deg[n] : 0;
  l[threadIdx.x] = v; __syncthreads();
  for (int s = 128; s; s >>= 1) { if (threadIdx.x < s) l[threadIdx.x] += l[threadIdx.x + s]; __syncthreads(); }
  if (threadIdx.x == 0) part[blockIdx.x] = l[0];
}
__global__ void k_scan_root(int* __restrict__ part, int P) {
  __shared__ int l[256];
  int t = threadIdx.x;
  int v = (t < P) ? part[t] : 0;
  l[t] = v; __syncthreads();
  for (int off = 1; off < 256; off <<= 1) {
    int x = (t >= off) ? l[t - off] : 0; __syncthreads();
    l[t] += x; __syncthreads();
  }
  if (t < P) part[t] = l[t] - v;  // exclusive
}
__global__ void k_scan_final(const int* __restrict__ deg, const int* __restrict__ part,
                             int* __restrict__ rowptr, int* __restrict__ cursor, int N) {
  __shared__ int l[256];
  int t = threadIdx.x, n = blockIdx.x * 256 + t;
  int v = (n < N) ? deg[n] : 0;
  l[t] = v; __syncthreads();
  for (int off = 1; off < 256; off <<= 1) {
    int x = (t >= off) ? l[t - off] : 0; __syncthreads();
    l[t] += x; __syncthreads();
  }
  if (n < N) { int rp = part[blockIdx.x] + l[t] - v; rowptr[n] = rp; cursor[n] = rp; }
}

// scatter BOTH CSRs: dst-CSR rec = {src(int bits), e0, e1, _}; src-CSR nbr = dst id.
__global__ void k_csr_scatter(const int* __restrict__ src, const int* __restrict__ dst,
                              const float* __restrict__ eattr2,
                              int* __restrict__ cursor_d, int* __restrict__ cursor_s,
                              float4* __restrict__ rec, int* __restrict__ srcnbr, int E) {
  int e = blockIdx.x * blockDim.x + threadIdx.x;
  if (e >= E) return;
  int s = src[e], d = dst[e];
  int pos = atomicAdd(&cursor_d[d], 1);
  float2 ev = *(const float2*)&eattr2[2 * e];
  float4 r;
  r.x = __int_as_float(s); r.y = ev.x; r.z = ev.y; r.w = 0.f;
  rec[pos] = r;
  int pos2 = atomicAdd(&cursor_s[s], 1);
  srcnbr[pos2] = d;
}

// C[N,*] = A[N,K] @ W[K,128], f32; output stored INTERLEAVED: C[n*128 + 2*c + head]
// where head = col>>6, c = col&63. W fully staged in LDS, 32 rows/block.
template<int K>
__global__ __launch_bounds__(256)
void k_gemm(const float* __restrict__ A, const float* __restrict__ W,
            float* __restrict__ C, int N) {
  __shared__ float Wl[K * 128];
  __shared__ float Al[32 * K];
  int tid = threadIdx.x;
  for (int i = tid * 4; i < K * 128; i += 256 * 4)
    *(float4*)&Wl[i] = *(const float4*)&W[i];
  int row0 = blockIdx.x * 32;
  for (int i = tid * 4; i < 32 * K; i += 256 * 4) {
    int r = i / K, c = i % K;
    int gr = row0 + r;
    float4 v = make_float4(0.f, 0.f, 0.f, 0.f);
    if (gr < N) v = *(const float4*)&A[(long long)gr * K + c];
    *(float4*)&Al[r * K + c] = v;
  }
  __syncthreads();
  int col = tid & 127;
  int ocol = ((col & 63) << 1) + (col >> 6);  // interleaved output column
  int rbase = (tid >> 7) * 16;
  float acc[16];
#pragma unroll
  for (int r = 0; r < 16; ++r) acc[r] = 0.f;
  for (int k = 0; k < K; ++k) {
    float w = Wl[k * 128 + col];
#pragma unroll
    for (int r = 0; r < 16; ++r) acc[r] += Al[(rbase + r) * K + k] * w;
  }
#pragma unroll
  for (int r = 0; r < 16; ++r) {
    int gr = row0 + rbase + r;
    if (gr < N) C[(long long)gr * 128 + ocol] = acc[r];
  }
}

// per-node attention scalars packed: asd[n] = {as0, as1, ad0, ad1}. One wave/node.
// h interleaved: h[n*128 + 2*lane] = head0, +1 = head1.
__global__ void k_att_nodes(const float* __restrict__ h,
                            const float* __restrict__ atts, const float* __restrict__ attd,
                            float* __restrict__ asd, int N) {
  int idx = blockIdx.x * blockDim.x + threadIdx.x;
  int n = idx >> 6, lane = idx & 63;
  if (n >= N) return;
  float2 v = *(const float2*)&h[(long long)n * 128 + 2 * lane];
  float ps0 = v.x * atts[lane];
  float ps1 = v.y * atts[64 + lane];
  float pd0 = v.x * attd[lane];
  float pd1 = v.y * attd[64 + lane];
  for (int off = 32; off; off >>= 1) {
    ps0 += __shfl_down(ps0, off);
    ps1 += __shfl_down(ps1, off);
    pd0 += __shfl_down(pd0, off);
    pd1 += __shfl_down(pd1, off);
  }
  if (lane == 0) {
    asd[4 * n] = ps0; asd[4 * n + 1] = ps1;
    asd[4 * n + 2] = pd0; asd[4 * n + 3] = pd1;
  }
}

// Fused GAT edge phase, pull-mode. One wave per dst node.
template<bool RELU>
__global__ __launch_bounds__(256)
void k_gat_pull(const int* __restrict__ rowptr, const float4* __restrict__ rec,
                const float* __restrict__ asd, const float* __restrict__ h,
                const float* __restrict__ we, const float* __restrict__ bias,
                float* __restrict__ out, int N, int E) {
  int wv = threadIdx.x >> 6, lane = threadIdx.x & 63;
  int d = blockIdx.x * 4 + wv;
  if (d >= N) return;
  int r0 = rowptr[d];
  int r1 = (d + 1 < N) ? rowptr[d + 1] : E;
  int deg = r1 - r0;
  float4 Ad = *(const float4*)&asd[4 * d];
  float w0 = we[0], w1 = we[1], w2 = we[2], w3 = we[3];
  float den0 = 0.f, den1 = 0.f, acc0 = 0.f, acc1 = 0.f, se0 = 0.f, se1 = 0.f;
  for (int cb = 0; cb < deg; cb += 64) {
    int j = cb + lane;
    int s = 0; float ea0 = 0.f, ea1 = 0.f, e0 = 0.f, e1 = 0.f;
    if (j < deg) {
      float4 rc = rec[r0 + j];
      s = __float_as_int(rc.x); e0 = rc.y; e1 = rc.z;
      float4 As = *(const float4*)&asd[4 * s];
      float x0 = As.x + Ad.z + e0 * w0 + e1 * w1;
      float x1 = As.y + Ad.w + e0 * w2 + e1 * w3;
      x0 = x0 >= 0.f ? x0 : 0.2f * x0;
      x1 = x1 >= 0.f ? x1 : 0.2f * x1;
      ea0 = expf(x0); ea1 = expf(x1);
    }
    float t0 = ea0, t1 = ea1, t2 = e0, t3 = e1;
    for (int off = 32; off; off >>= 1) {
      t0 += __shfl_xor(t0, off); t1 += __shfl_xor(t1, off);
      t2 += __shfl_xor(t2, off); t3 += __shfl_xor(t3, off);
    }
    den0 += t0; den1 += t1; se0 += t2; se1 += t3;
    int m = min(64, deg - cb);
    for (int j2 = 0; j2 < m; ++j2) {
      int sj = __shfl(s, j2);
      float a0 = __shfl(ea0, j2);
      float a1 = __shfl(ea1, j2);
      float2 hv = *(const float2*)&h[(long long)sj * 128 + 2 * lane];
      acc0 += a0 * hv.x;
      acc1 += a1 * hv.y;
    }
  }
  // self-loop: edge_attr = mean of incident (by dst) eattr
  float id = 1.0f / fmaxf((float)deg, 1.0f);
  float le0 = se0 * id, le1 = se1 * id;
  float x0 = Ad.x + Ad.z + le0 * w0 + le1 * w1;
  float x1 = Ad.y + Ad.w + le0 * w2 + le1 * w3;
  x0 = x0 >= 0.f ? x0 : 0.2f * x0;
  x1 = x1 >= 0.f ? x1 : 0.2f * x1;
  float eas0 = expf(x0), eas1 = expf(x1);
  den0 += eas0; den1 += eas1;
  float2 hd = *(const float2*)&h[(long long)d * 128 + 2 * lane];
  acc0 += eas0 * hd.x;
  acc1 += eas1 * hd.y;
  float v = 0.5f * (acc0 / (den0 + 1e-16f) + acc1 / (den1 + 1e-16f)) + bias[lane];
  if (RELU) v = fmaxf(v, 0.f);
  out[(long long)d * 64 + lane] = v;
}

// per-node heads: p_n = softmax(h@Wn + bn); fgn = {q=r1-r0, nab0, 0, 0}. One wave/node.
__global__ void k_head(const float* __restrict__ hh, const float* __restrict__ Wn,
                       const float* __restrict__ bn, const float* __restrict__ Wec,
                       float* __restrict__ p_n, float* __restrict__ fgn, int N) {
  int idx = blockIdx.x * blockDim.x + threadIdx.x;
  int n = idx >> 6, lane = idx & 63;
  if (n >= N) return;
  float v = hh[(long long)n * 64 + lane];
  float p[7];
#pragma unroll
  for (int j = 0; j < 5; ++j) p[j] = v * Wn[lane * 5 + j];
  p[5] = v * Wec[lane * 2];
  p[6] = v * Wec[lane * 2 + 1];
  for (int off = 32; off; off >>= 1) {
#pragma unroll
    for (int j = 0; j < 7; ++j) p[j] += __shfl_down(p[j], off);
  }
  if (lane == 0) {
    float l[5]; float m = -1e30f;
#pragma unroll
    for (int j = 0; j < 5; ++j) { l[j] = p[j] + bn[j]; m = fmaxf(m, l[j]); }
    float ssum = 0.f;
#pragma unroll
    for (int j = 0; j < 5; ++j) { l[j] = expf(l[j] - m); ssum += l[j]; }
    float inv = 1.0f / ssum;
#pragma unroll
    for (int j = 0; j < 5; ++j) p_n[5 * n + j] = l[j] * inv;
    fgn[4 * n]     = p[6] - p[5];            // q = r1 - r0
    fgn[4 * n + 1] = (ssum - l[0]) * inv;    // nab0 = 1 - p_n[:,0]
    fgn[4 * n + 2] = 0.f;
    fgn[4 * n + 3] = 0.f;
  }
}

// eab after iteration chain: 1 / (1 + exp(-t)/c), c = prod of factors. Stable for any t.
__device__ __forceinline__ float fg_eab(float t, float c) {
  return 1.0f / (1.0f + expf(-t) / c);
}

// factor-graph node-pull iteration. One thread per node: loop both CSR rows,
// gather fgn[other] (L2-hit), recompute edge odds-chain, accumulate eab, update p_n.
// ITER==1: eab after 1st edge update (uses nab0); writes p_n^1 and fgn.z=nab1.
// ITER==2: eab after 2nd edge update (uses nab0 and nab1); writes out_n logs.
template<int ITER>
__global__ void k_fg_pull(const int* __restrict__ rowptr_d, const float4* __restrict__ rec,
                          const int* __restrict__ rowptr_s, const int* __restrict__ srcnbr,
                          float* __restrict__ p_n, float* __restrict__ fgn,
                          const float* __restrict__ consts, float* __restrict__ out_n,
                          int N, int E) {
  int n = blockIdx.x * blockDim.x + threadIdx.x;
  if (n >= N) return;
  float4 F = *(const float4*)&fgn[4 * n];
  float q = F.x, nab0 = F.y, nab1 = F.z;
  float avg_ef = consts[8], avg_nf = consts[9], dbec = consts[10];
  int rd0 = rowptr_d[n], rd1 = (n + 1 < N) ? rowptr_d[n + 1] : E;
  int rs0 = rowptr_s[n], rs1 = (n + 1 < N) ? rowptr_s[n + 1] : E;
  float s_eab = 0.f;
  for (int j = rd0; j < rd1; ++j) {
    float4 Fo = *(const float4*)&fgn[4 * __float_as_int(rec[j].x)];
    float t = 0.5f * (q + Fo.x) + dbec;
    float c = 1.0f + fmaxf(nab0, Fo.y) * avg_ef;
    if (ITER == 2) c *= 1.0f + fmaxf(nab1, Fo.z) * avg_ef;
    s_eab += fg_eab(t, c);
  }
  for (int j = rs0; j < rs1; ++j) {
    float4 Fo = *(const float4*)&fgn[4 * srcnbr[j]];
    float t = 0.5f * (q + Fo.x) + dbec;
    float c = 1.0f + fmaxf(nab0, Fo.y) * avg_ef;
    if (ITER == 2) c *= 1.0f + fmaxf(nab1, Fo.z) * avg_ef;
    s_eab += fg_eab(t, c);
  }
  float deg = (float)((rd1 - rd0) + (rs1 - rs0));
  float mean = s_eab / (deg + 1e-6f);
  float f = 1.0f + mean * avg_nf;
  float p0 = p_n[5 * n], p1 = p_n[5 * n + 1], p2 = p_n[5 * n + 2],
        p3 = p_n[5 * n + 3], p4 = p_n[5 * n + 4];
  float rest = (p1 + p2 + p3 + p4) * f;
  float inv = 1.0f / (p0 + rest);
  if (ITER == 1) {
    p_n[5 * n]     = p0 * inv;
    p_n[5 * n + 1] = p1 * f * inv;
    p_n[5 * n + 2] = p2 * f * inv;
    p_n[5 * n + 3] = p3 * f * inv;
    p_n[5 * n + 4] = p4 * f * inv;
    fgn[4 * n + 2] = rest * inv;   // nab1 = 1 - p0'
  } else {
    out_n[5 * n]     = logf(p0 * inv + 1e-9f);
    out_n[5 * n + 1] = logf(p1 * f * inv + 1e-9f);
    out_n[5 * n + 2] = logf(p2 * f * inv + 1e-9f);
    out_n[5 * n + 3] = logf(p3 * f * inv + 1e-9f);
    out_n[5 * n + 4] = logf(p4 * f * inv + 1e-9f);
  }
}

// final edge output: recompute full odds-chain, write log p_e^2. Coalesced.
__global__ void k_fg_edge_out(const int* __restrict__ src, const int* __restrict__ dst,
                              const float* __restrict__ fgn, const float* __restrict__ consts,
                              float* __restrict__ out_e, int E) {
  int e = blockIdx.x * blockDim.x + threadIdx.x;
  if (e >= E) return;
  float avg_ef = consts[8], dbec = consts[10];
  float4 Fs = *(const float4*)&fgn[4 * src[e]];
  float4 Fd = *(const float4*)&fgn[4 * dst[e]];
  float t = 0.5f * (Fs.x + Fd.x) + dbec;
  float c = (1.0f + fmaxf(Fs.y, Fd.y) * avg_ef) * (1.0f + fmaxf(Fs.z, Fd.z) * avg_ef);
  float pe1 = 1.0f / (1.0f + expf(-t) / c);
  float pe0 = 1.0f / (1.0f + c * expf(t));
  *(float2*)&out_e[2 * e] = make_float2(logf(pe0 + 1e-9f), logf(pe1 + 1e-9f));
}

extern "C" void kernel_launch(void* const* d_in, const int* in_sizes, int n_in,
                              void* d_out, int out_size, void* d_ws, size_t ws_size,
                              hipStream_t stream) {
  const float* x      = (const float*)d_in[0];
  const int*   ei     = (const int*)d_in[1];
  const float* eattr  = (const float*)d_in[2];
  const float* W1     = (const float*)d_in[3];
  const float* atts1  = (const float*)d_in[4];
  const float* attd1  = (const float*)d_in[5];
  const float* We1    = (const float*)d_in[6];
  const float* atte1  = (const float*)d_in[7];
  const float* b1     = (const float*)d_in[8];
  const float* W2     = (const float*)d_in[9];
  const float* atts2  = (const float*)d_in[10];
  const float* attd2  = (const float*)d_in[11];
  const float* We2    = (const float*)d_in[12];
  const float* atte2  = (const float*)d_in[13];
  const float* b2     = (const float*)d_in[14];
  const float* Wn     = (const float*)d_in[15];
  const float* bn     = (const float*)d_in[16];
  const float* Wec    = (const float*)d_in[17];
  const float* bec    = (const float*)d_in[18];
  const float* nodefw = (const float*)d_in[19];
  const float* edgefw = (const float*)d_in[20];

  const int N = in_sizes[0] / 128;
  const int E = in_sizes[1] / 2;
  const int* src = ei;
  const int* dst = ei + E;

  float* out_n = (float*)d_out;
  float* out_e = out_n + (long long)N * 5;

  // ---- workspace carve (f32 units, 16B aligned) ----
  size_t off = 0;
  float* base = (float*)d_ws;
  auto carve = [&](size_t nelem) { float* p = base + off; off += (nelem + 3) & ~(size_t)3; return p; };
  float* h        = carve((size_t)N * 128);
  float* x2       = carve((size_t)N * 64);
  float* asd      = carve((size_t)N * 4);
  float* rec      = carve((size_t)E * 4);     // float4 dst-CSR records
  int*   srcnbr   = (int*)carve((size_t)E);   // src-CSR neighbor ids
  int*   deg_dst  = (int*)carve((size_t)N);
  int*   deg_src  = (int*)carve((size_t)N);
  int*   rowptr_d = (int*)carve((size_t)N);
  int*   cursor_d = (int*)carve((size_t)N);
  int*   rowptr_s = (int*)carve((size_t)N);
  int*   cursor_s = (int*)carve((size_t)N);
  int*   part     = (int*)carve(256);
  float* p_n      = carve((size_t)N * 5);
  float* fgn      = carve((size_t)N * 4);
  float* consts   = carve(16);
  if (off * sizeof(float) > ws_size) return;  // insufficient scratch: fail loudly

  const int B = 256;
  const int gE  = cdiv_i(E, B);
  const int gN  = cdiv_i(N, B);
  const int gNW = cdiv_i((long long)N * 64, B);   // wave-per-node kernels
  const int P   = cdiv_i(N, 256);                 // scan partials (196)

  // ---- graph prep: degrees + both CSRs ----
  hipMemsetAsync(deg_dst, 0, (size_t)N * 4, stream);
  hipMemsetAsync(deg_src, 0, (size_t)N * 4, stream);
  k_prep_consts<<<1, 64, 0, stream>>>(We1, atte1, We2, atte2, nodefw, edgefw, bec, consts);
  k_degrees<<<gE, B, 0, stream>>>(src, dst, deg_dst, deg_src, E);
  k_scan_partial<<<P, 256, 0, stream>>>(deg_dst, part, N);
  k_scan_root<<<1, 256, 0, stream>>>(part, P);
  k_scan_final<<<P, 256, 0, stream>>>(deg_dst, part, rowptr_d, cursor_d, N);
  k_scan_partial<<<P, 256, 0, stream>>>(deg_src, part, N);
  k_scan_root<<<1, 256, 0, stream>>>(part, P);
  k_scan_final<<<P, 256, 0, stream>>>(deg_src, part, rowptr_s, cursor_s, N);
  k_csr_scatter<<<gE, B, 0, stream>>>(src, dst, eattr, cursor_d, cursor_s,
                                      (float4*)rec, srcnbr, E);

  // ---- GAT layer 1 ----
  k_gemm<128><<<cdiv_i(N, 32), 256, 0, stream>>>(x, W1, h, N);
  k_att_nodes<<<gNW, B, 0, stream>>>(h, atts1, attd1, asd, N);
  k_gat_pull<true><<<cdiv_i(N, 4), 256, 0, stream>>>(rowptr_d, (const float4*)rec, asd, h,
                                                     consts, b1, x2, N, E);

  // ---- GAT layer 2 ----
  k_gemm<64><<<cdiv_i(N, 32), 256, 0, stream>>>(x2, W2, h, N);
  k_att_nodes<<<gNW, B, 0, stream>>>(h, atts2, attd2, asd, N);
  k_gat_pull<false><<<cdiv_i(N, 4), 256, 0, stream>>>(rowptr_d, (const float4*)rec, asd, h,
                                                      consts + 4, b2, x2, N, E);

  // ---- heads ----
  k_head<<<gNW, B, 0, stream>>>(x2, Wn, bn, Wec, p_n, fgn, N);

  // ---- factor graph: 2 pull iterations + edge output ----
  k_fg_pull<1><<<gN, B, 0, stream>>>(rowptr_d, (const float4*)rec, rowptr_s, srcnbr,
                                     p_n, fgn, consts, nullptr, N, E);
  k_fg_pull<2><<<gN, B, 0, stream>>>(rowptr_d, (const float4*)rec, rowptr_s, srcnbr,
                                     p_n, fgn, consts, out_n, N, E);
  k_fg_edge_out<<<gE, B, 0, stream>>>(src, dst, fgn, consts, out_e, E);
}

// Round 5
// 433.242 us; speedup vs baseline: 2.9625x; 1.3654x over previous
//
#include <hip/hip_runtime.h>
#include <math.h>

// GraphRespiratory: 2-layer GAT (edge features, concat=False) + factor graph.
// N=50000, E=800000, IN=128, HID=OUT=64, H=2, NC=5, EC=2, NUM_ITER=2, GAMMA=1.
//
// R4 changes vs R3:
//  - CSR build replaced by bucketed two-level construction:
//    hist -> scan(196) -> block-staged bucket scatter (1 global atomic per
//    bucket per block, chunky tail writes) -> per-bucket LDS counting sort
//    (writes confined to the block's own 64KB window; emits rowptr directly).
//    k_degrees + 6 N-wide scan kernels deleted.
//  - Bucket staging buffers alias h (build completes before gemm writes h).

static inline int cdiv_i(long long a, long long b) { return (int)((a + b - 1) / b); }

#define BSH 8           // bucket shift: 256 nodes per bucket
#define CBK 8           // edges per thread in bucket scatter (2048/block)

// consts: [0..3] w_e1[h][k], [4..7] w_e2[h][k], [8] avg_ef, [9] avg_nf, [10] dbec
__global__ void k_prep_consts(const float* __restrict__ We1, const float* __restrict__ att_e1,
                              const float* __restrict__ We2, const float* __restrict__ att_e2,
                              const float* __restrict__ node_fw, const float* __restrict__ edge_fw,
                              const float* __restrict__ bec, float* __restrict__ consts) {
  if (blockIdx.x != 0 || threadIdx.x != 0) return;
  for (int h = 0; h < 2; ++h) {
    for (int k = 0; k < 2; ++k) {
      float s1 = 0.f, s2 = 0.f;
      for (int c = 0; c < 64; ++c) {
        s1 += We1[k * 128 + h * 64 + c] * att_e1[h * 64 + c];
        s2 += We2[k * 128 + h * 64 + c] * att_e2[h * 64 + c];
      }
      consts[h * 2 + k] = s1;
      consts[4 + h * 2 + k] = s2;
    }
  }
  float ef = 0.f;                      // edge_fw is [EC=2, NC=5]; mean of [1:,1:]
  for (int j = 1; j < 5; ++j) ef += edge_fw[5 + j];
  consts[8] = ef * 0.25f;
  float nf = 0.f;                      // node_fw is [NC=5, EC=2]; mean of [1:,1:]
  for (int i = 1; i < 5; ++i) nf += node_fw[i * 2 + 1];
  consts[9] = nf * 0.25f;
  consts[10] = bec[1] - bec[0];
}

// ---- bucketed CSR build ----
__global__ void k_bkt_hist(const int* __restrict__ src, const int* __restrict__ dst,
                           int* __restrict__ hist_d, int* __restrict__ hist_s,
                           int nbkt, int E) {
  __shared__ int hd[256], hs[256];
  int t = threadIdx.x;
  hd[t] = 0; hs[t] = 0;
  __syncthreads();
  for (int e = blockIdx.x * blockDim.x + t; e < E; e += gridDim.x * blockDim.x) {
    atomicAdd(&hd[dst[e] >> BSH], 1);
    atomicAdd(&hs[src[e] >> BSH], 1);
  }
  __syncthreads();
  if (t < nbkt) {
    if (hd[t]) atomicAdd(&hist_d[t], hd[t]);
    if (hs[t]) atomicAdd(&hist_s[t], hs[t]);
  }
}

// one block: exclusive-scan both histograms -> bases (nbkt+1) and cursors (in place)
__global__ void k_bkt_scan(int* __restrict__ cur_d, int* __restrict__ base_d,
                           int* __restrict__ cur_s, int* __restrict__ base_s, int nbkt) {
  __shared__ int l[256];
  int t = threadIdx.x;
  int v = (t < nbkt) ? cur_d[t] : 0;
  l[t] = v; __syncthreads();
  for (int off = 1; off < 256; off <<= 1) {
    int x = (t >= off) ? l[t - off] : 0; __syncthreads();
    l[t] += x; __syncthreads();
  }
  int incl = l[t];
  if (t < nbkt) { base_d[t] = incl - v; cur_d[t] = incl - v; }
  if (t == nbkt - 1) base_d[nbkt] = incl;
  __syncthreads();
  v = (t < nbkt) ? cur_s[t] : 0;
  l[t] = v; __syncthreads();
  for (int off = 1; off < 256; off <<= 1) {
    int x = (t >= off) ? l[t - off] : 0; __syncthreads();
    l[t] += x; __syncthreads();
  }
  incl = l[t];
  if (t < nbkt) { base_s[t] = incl - v; cur_s[t] = incl - v; }
  if (t == nbkt - 1) base_s[nbkt] = incl;
}

// block-staged bucket scatter: 2048 edges/block in regs; LDS per-bucket counts;
// one global atomicAdd per (bucket,block) to reserve; chunky tail writes.
__global__ __launch_bounds__(256)
void k_bkt_scatter(const int* __restrict__ src, const int* __restrict__ dst,
                   const float* __restrict__ eattr2,
                   int* __restrict__ cur_d, int* __restrict__ cur_s,
                   float4* __restrict__ stage_d, int2* __restrict__ stage_s,
                   int nbkt, int E) {
  __shared__ int cd[256], cs[256], bd[256], bs[256];
  int t = threadIdx.x;
  cd[t] = 0; cs[t] = 0;
  __syncthreads();
  int base = blockIdx.x * 256 * CBK;
  int s[CBK], d[CBK]; float e0[CBK], e1[CBK];
#pragma unroll
  for (int c = 0; c < CBK; ++c) {
    int e = base + c * 256 + t;
    if (e < E) {
      s[c] = src[e]; d[c] = dst[e];
      float2 ev = *(const float2*)&eattr2[2 * e];
      e0[c] = ev.x; e1[c] = ev.y;
      atomicAdd(&cd[d[c] >> BSH], 1);
      atomicAdd(&cs[s[c] >> BSH], 1);
    } else s[c] = -1;
  }
  __syncthreads();
  if (t < nbkt) {
    bd[t] = cd[t] ? atomicAdd(&cur_d[t], cd[t]) : 0;
    bs[t] = cs[t] ? atomicAdd(&cur_s[t], cs[t]) : 0;
    cd[t] = 0; cs[t] = 0;
  }
  __syncthreads();
#pragma unroll
  for (int c = 0; c < CBK; ++c) {
    if (s[c] < 0) continue;
    int db = d[c] >> BSH, sb = s[c] >> BSH;
    int pos = bd[db] + atomicAdd(&cd[db], 1);
    float4 r;
    r.x = __int_as_float(s[c]); r.y = e0[c]; r.z = e1[c]; r.w = __int_as_float(d[c]);
    stage_d[pos] = r;
    int pos2 = bs[sb] + atomicAdd(&cs[sb], 1);
    stage_s[pos2] = make_int2(s[c], d[c]);
  }
}

// per-bucket counting sort (dst side): emits rowptr_d + final rec.
// All writes confined to this block's [b0,b1) window.
__global__ __launch_bounds__(256)
void k_bkt_sort_d(const float4* __restrict__ stage, const int* __restrict__ base,
                  int* __restrict__ rowptr, float4* __restrict__ rec, int N) {
  int b = blockIdx.x, t = threadIdx.x;
  int nlo = b << BSH;
  int b0 = base[b], b1 = base[b + 1];
  __shared__ int cnt[256], cur[256], l[256];
  cnt[t] = 0;
  __syncthreads();
  for (int j = b0 + t; j < b1; j += 256)
    atomicAdd(&cnt[__float_as_int(stage[j].w) - nlo], 1);
  __syncthreads();
  int v = cnt[t];
  l[t] = v; __syncthreads();
  for (int off = 1; off < 256; off <<= 1) {
    int x = (t >= off) ? l[t - off] : 0; __syncthreads();
    l[t] += x; __syncthreads();
  }
  int excl = l[t] - v;
  if (nlo + t < N) rowptr[nlo + t] = b0 + excl;
  cur[t] = excl;
  __syncthreads();
  for (int j = b0 + t; j < b1; j += 256) {
    float4 r = stage[j];
    int d = __float_as_int(r.w) - nlo;
    int pos = b0 + atomicAdd(&cur[d], 1);
    rec[pos] = r;
  }
}

// per-bucket counting sort (src side): emits rowptr_s + srcnbr (payload = dst).
__global__ __launch_bounds__(256)
void k_bkt_sort_s(const int2* __restrict__ stage, const int* __restrict__ base,
                  int* __restrict__ rowptr, int* __restrict__ srcnbr, int N) {
  int b = blockIdx.x, t = threadIdx.x;
  int nlo = b << BSH;
  int b0 = base[b], b1 = base[b + 1];
  __shared__ int cnt[256], cur[256], l[256];
  cnt[t] = 0;
  __syncthreads();
  for (int j = b0 + t; j < b1; j += 256)
    atomicAdd(&cnt[stage[j].x - nlo], 1);
  __syncthreads();
  int v = cnt[t];
  l[t] = v; __syncthreads();
  for (int off = 1; off < 256; off <<= 1) {
    int x = (t >= off) ? l[t - off] : 0; __syncthreads();
    l[t] += x; __syncthreads();
  }
  int excl = l[t] - v;
  if (nlo + t < N) rowptr[nlo + t] = b0 + excl;
  cur[t] = excl;
  __syncthreads();
  for (int j = b0 + t; j < b1; j += 256) {
    int2 r = stage[j];
    int pos = b0 + atomicAdd(&cur[r.x - nlo], 1);
    srcnbr[pos] = r.y;
  }
}

// C[N,*] = A[N,K] @ W[K,128], f32; output stored INTERLEAVED: C[n*128 + 2*c + head]
// where head = col>>6, c = col&63. W fully staged in LDS, 32 rows/block.
template<int K>
__global__ __launch_bounds__(256)
void k_gemm(const float* __restrict__ A, const float* __restrict__ W,
            float* __restrict__ C, int N) {
  __shared__ float Wl[K * 128];
  __shared__ float Al[32 * K];
  int tid = threadIdx.x;
  for (int i = tid * 4; i < K * 128; i += 256 * 4)
    *(float4*)&Wl[i] = *(const float4*)&W[i];
  int row0 = blockIdx.x * 32;
  for (int i = tid * 4; i < 32 * K; i += 256 * 4) {
    int r = i / K, c = i % K;
    int gr = row0 + r;
    float4 v = make_float4(0.f, 0.f, 0.f, 0.f);
    if (gr < N) v = *(const float4*)&A[(long long)gr * K + c];
    *(float4*)&Al[r * K + c] = v;
  }
  __syncthreads();
  int col = tid & 127;
  int ocol = ((col & 63) << 1) + (col >> 6);  // interleaved output column
  int rbase = (tid >> 7) * 16;
  float acc[16];
#pragma unroll
  for (int r = 0; r < 16; ++r) acc[r] = 0.f;
  for (int k = 0; k < K; ++k) {
    float w = Wl[k * 128 + col];
#pragma unroll
    for (int r = 0; r < 16; ++r) acc[r] += Al[(rbase + r) * K + k] * w;
  }
#pragma unroll
  for (int r = 0; r < 16; ++r) {
    int gr = row0 + rbase + r;
    if (gr < N) C[(long long)gr * 128 + ocol] = acc[r];
  }
}

// per-node attention scalars packed: asd[n] = {as0, as1, ad0, ad1}. One wave/node.
// h interleaved: h[n*128 + 2*lane] = head0, +1 = head1.
__global__ void k_att_nodes(const float* __restrict__ h,
                            const float* __restrict__ atts, const float* __restrict__ attd,
                            float* __restrict__ asd, int N) {
  int idx = blockIdx.x * blockDim.x + threadIdx.x;
  int n = idx >> 6, lane = idx & 63;
  if (n >= N) return;
  float2 v = *(const float2*)&h[(long long)n * 128 + 2 * lane];
  float ps0 = v.x * atts[lane];
  float ps1 = v.y * atts[64 + lane];
  float pd0 = v.x * attd[lane];
  float pd1 = v.y * attd[64 + lane];
  for (int off = 32; off; off >>= 1) {
    ps0 += __shfl_down(ps0, off);
    ps1 += __shfl_down(ps1, off);
    pd0 += __shfl_down(pd0, off);
    pd1 += __shfl_down(pd1, off);
  }
  if (lane == 0) {
    asd[4 * n] = ps0; asd[4 * n + 1] = ps1;
    asd[4 * n + 2] = pd0; asd[4 * n + 3] = pd1;
  }
}

// Fused GAT edge phase, pull-mode. One wave per dst node.
template<bool RELU>
__global__ __launch_bounds__(256)
void k_gat_pull(const int* __restrict__ rowptr, const float4* __restrict__ rec,
                const float* __restrict__ asd, const float* __restrict__ h,
                const float* __restrict__ we, const float* __restrict__ bias,
                float* __restrict__ out, int N, int E) {
  int wv = threadIdx.x >> 6, lane = threadIdx.x & 63;
  int d = blockIdx.x * 4 + wv;
  if (d >= N) return;
  int r0 = rowptr[d];
  int r1 = (d + 1 < N) ? rowptr[d + 1] : E;
  int deg = r1 - r0;
  float4 Ad = *(const float4*)&asd[4 * d];
  float w0 = we[0], w1 = we[1], w2 = we[2], w3 = we[3];
  float den0 = 0.f, den1 = 0.f, acc0 = 0.f, acc1 = 0.f, se0 = 0.f, se1 = 0.f;
  for (int cb = 0; cb < deg; cb += 64) {
    int j = cb + lane;
    int s = 0; float ea0 = 0.f, ea1 = 0.f, e0 = 0.f, e1 = 0.f;
    if (j < deg) {
      float4 rc = rec[r0 + j];
      s = __float_as_int(rc.x); e0 = rc.y; e1 = rc.z;
      float4 As = *(const float4*)&asd[4 * s];
      float x0 = As.x + Ad.z + e0 * w0 + e1 * w1;
      float x1 = As.y + Ad.w + e0 * w2 + e1 * w3;
      x0 = x0 >= 0.f ? x0 : 0.2f * x0;
      x1 = x1 >= 0.f ? x1 : 0.2f * x1;
      ea0 = expf(x0); ea1 = expf(x1);
    }
    float t0 = ea0, t1 = ea1, t2 = e0, t3 = e1;
    for (int off = 32; off; off >>= 1) {
      t0 += __shfl_xor(t0, off); t1 += __shfl_xor(t1, off);
      t2 += __shfl_xor(t2, off); t3 += __shfl_xor(t3, off);
    }
    den0 += t0; den1 += t1; se0 += t2; se1 += t3;
    int m = min(64, deg - cb);
    for (int j2 = 0; j2 < m; ++j2) {
      int sj = __shfl(s, j2);
      float a0 = __shfl(ea0, j2);
      float a1 = __shfl(ea1, j2);
      float2 hv = *(const float2*)&h[(long long)sj * 128 + 2 * lane];
      acc0 += a0 * hv.x;
      acc1 += a1 * hv.y;
    }
  }
  // self-loop: edge_attr = mean of incident (by dst) eattr
  float id = 1.0f / fmaxf((float)deg, 1.0f);
  float le0 = se0 * id, le1 = se1 * id;
  float x0 = Ad.x + Ad.z + le0 * w0 + le1 * w1;
  float x1 = Ad.y + Ad.w + le0 * w2 + le1 * w3;
  x0 = x0 >= 0.f ? x0 : 0.2f * x0;
  x1 = x1 >= 0.f ? x1 : 0.2f * x1;
  float eas0 = expf(x0), eas1 = expf(x1);
  den0 += eas0; den1 += eas1;
  float2 hd = *(const float2*)&h[(long long)d * 128 + 2 * lane];
  acc0 += eas0 * hd.x;
  acc1 += eas1 * hd.y;
  float v = 0.5f * (acc0 / (den0 + 1e-16f) + acc1 / (den1 + 1e-16f)) + bias[lane];
  if (RELU) v = fmaxf(v, 0.f);
  out[(long long)d * 64 + lane] = v;
}

// per-node heads: p_n = softmax(h@Wn + bn); fgn = {q=r1-r0, nab0, 0, 0}. One wave/node.
__global__ void k_head(const float* __restrict__ hh, const float* __restrict__ Wn,
                       const float* __restrict__ bn, const float* __restrict__ Wec,
                       float* __restrict__ p_n, float* __restrict__ fgn, int N) {
  int idx = blockIdx.x * blockDim.x + threadIdx.x;
  int n = idx >> 6, lane = idx & 63;
  if (n >= N) return;
  float v = hh[(long long)n * 64 + lane];
  float p[7];
#pragma unroll
  for (int j = 0; j < 5; ++j) p[j] = v * Wn[lane * 5 + j];
  p[5] = v * Wec[lane * 2];
  p[6] = v * Wec[lane * 2 + 1];
  for (int off = 32; off; off >>= 1) {
#pragma unroll
    for (int j = 0; j < 7; ++j) p[j] += __shfl_down(p[j], off);
  }
  if (lane == 0) {
    float l[5]; float m = -1e30f;
#pragma unroll
    for (int j = 0; j < 5; ++j) { l[j] = p[j] + bn[j]; m = fmaxf(m, l[j]); }
    float ssum = 0.f;
#pragma unroll
    for (int j = 0; j < 5; ++j) { l[j] = expf(l[j] - m); ssum += l[j]; }
    float inv = 1.0f / ssum;
#pragma unroll
    for (int j = 0; j < 5; ++j) p_n[5 * n + j] = l[j] * inv;
    fgn[4 * n]     = p[6] - p[5];            // q = r1 - r0
    fgn[4 * n + 1] = (ssum - l[0]) * inv;    // nab0 = 1 - p_n[:,0]
    fgn[4 * n + 2] = 0.f;
    fgn[4 * n + 3] = 0.f;
  }
}

// eab after iteration chain: 1 / (1 + exp(-t)/c), c = prod of factors. Stable for any t.
__device__ __forceinline__ float fg_eab(float t, float c) {
  return 1.0f / (1.0f + expf(-t) / c);
}

// factor-graph node-pull iteration. One thread per node: loop both CSR rows,
// gather fgn[other] (L2-hit), recompute edge odds-chain, accumulate eab, update p_n.
template<int ITER>
__global__ void k_fg_pull(const int* __restrict__ rowptr_d, const float4* __restrict__ rec,
                          const int* __restrict__ rowptr_s, const int* __restrict__ srcnbr,
                          float* __restrict__ p_n, float* __restrict__ fgn,
                          const float* __restrict__ consts, float* __restrict__ out_n,
                          int N, int E) {
  int n = blockIdx.x * blockDim.x + threadIdx.x;
  if (n >= N) return;
  float4 F = *(const float4*)&fgn[4 * n];
  float q = F.x, nab0 = F.y, nab1 = F.z;
  float avg_ef = consts[8], avg_nf = consts[9], dbec = consts[10];
  int rd0 = rowptr_d[n], rd1 = (n + 1 < N) ? rowptr_d[n + 1] : E;
  int rs0 = rowptr_s[n], rs1 = (n + 1 < N) ? rowptr_s[n + 1] : E;
  float s_eab = 0.f;
  for (int j = rd0; j < rd1; ++j) {
    float4 Fo = *(const float4*)&fgn[4 * __float_as_int(rec[j].x)];
    float t = 0.5f * (q + Fo.x) + dbec;
    float c = 1.0f + fmaxf(nab0, Fo.y) * avg_ef;
    if (ITER == 2) c *= 1.0f + fmaxf(nab1, Fo.z) * avg_ef;
    s_eab += fg_eab(t, c);
  }
  for (int j = rs0; j < rs1; ++j) {
    float4 Fo = *(const float4*)&fgn[4 * srcnbr[j]];
    float t = 0.5f * (q + Fo.x) + dbec;
    float c = 1.0f + fmaxf(nab0, Fo.y) * avg_ef;
    if (ITER == 2) c *= 1.0f + fmaxf(nab1, Fo.z) * avg_ef;
    s_eab += fg_eab(t, c);
  }
  float deg = (float)((rd1 - rd0) + (rs1 - rs0));
  float mean = s_eab / (deg + 1e-6f);
  float f = 1.0f + mean * avg_nf;
  float p0 = p_n[5 * n], p1 = p_n[5 * n + 1], p2 = p_n[5 * n + 2],
        p3 = p_n[5 * n + 3], p4 = p_n[5 * n + 4];
  float rest = (p1 + p2 + p3 + p4) * f;
  float inv = 1.0f / (p0 + rest);
  if (ITER == 1) {
    p_n[5 * n]     = p0 * inv;
    p_n[5 * n + 1] = p1 * f * inv;
    p_n[5 * n + 2] = p2 * f * inv;
    p_n[5 * n + 3] = p3 * f * inv;
    p_n[5 * n + 4] = p4 * f * inv;
    fgn[4 * n + 2] = rest * inv;   // nab1 = 1 - p0'
  } else {
    out_n[5 * n]     = logf(p0 * inv + 1e-9f);
    out_n[5 * n + 1] = logf(p1 * f * inv + 1e-9f);
    out_n[5 * n + 2] = logf(p2 * f * inv + 1e-9f);
    out_n[5 * n + 3] = logf(p3 * f * inv + 1e-9f);
    out_n[5 * n + 4] = logf(p4 * f * inv + 1e-9f);
  }
}

// final edge output: recompute full odds-chain, write log p_e^2. Coalesced.
__global__ void k_fg_edge_out(const int* __restrict__ src, const int* __restrict__ dst,
                              const float* __restrict__ fgn, const float* __restrict__ consts,
                              float* __restrict__ out_e, int E) {
  int e = blockIdx.x * blockDim.x + threadIdx.x;
  if (e >= E) return;
  float avg_ef = consts[8], dbec = consts[10];
  float4 Fs = *(const float4*)&fgn[4 * src[e]];
  float4 Fd = *(const float4*)&fgn[4 * dst[e]];
  float t = 0.5f * (Fs.x + Fd.x) + dbec;
  float c = (1.0f + fmaxf(Fs.y, Fd.y) * avg_ef) * (1.0f + fmaxf(Fs.z, Fd.z) * avg_ef);
  float pe1 = 1.0f / (1.0f + expf(-t) / c);
  float pe0 = 1.0f / (1.0f + c * expf(t));
  *(float2*)&out_e[2 * e] = make_float2(logf(pe0 + 1e-9f), logf(pe1 + 1e-9f));
}

extern "C" void kernel_launch(void* const* d_in, const int* in_sizes, int n_in,
                              void* d_out, int out_size, void* d_ws, size_t ws_size,
                              hipStream_t stream) {
  const float* x      = (const float*)d_in[0];
  const int*   ei     = (const int*)d_in[1];
  const float* eattr  = (const float*)d_in[2];
  const float* W1     = (const float*)d_in[3];
  const float* atts1  = (const float*)d_in[4];
  const float* attd1  = (const float*)d_in[5];
  const float* We1    = (const float*)d_in[6];
  const float* atte1  = (const float*)d_in[7];
  const float* b1     = (const float*)d_in[8];
  const float* W2     = (const float*)d_in[9];
  const float* atts2  = (const float*)d_in[10];
  const float* attd2  = (const float*)d_in[11];
  const float* We2    = (const float*)d_in[12];
  const float* atte2  = (const float*)d_in[13];
  const float* b2     = (const float*)d_in[14];
  const float* Wn     = (const float*)d_in[15];
  const float* bn     = (const float*)d_in[16];
  const float* Wec    = (const float*)d_in[17];
  const float* bec    = (const float*)d_in[18];
  const float* nodefw = (const float*)d_in[19];
  const float* edgefw = (const float*)d_in[20];

  const int N = in_sizes[0] / 128;
  const int E = in_sizes[1] / 2;
  const int* src = ei;
  const int* dst = ei + E;
  const int nbkt = (N + 255) >> BSH;   // 196 (assumes N <= 65536)

  float* out_n = (float*)d_out;
  float* out_e = out_n + (long long)N * 5;

  // ---- workspace carve (f32 units, 16B aligned) ----
  size_t off = 0;
  float* base = (float*)d_ws;
  auto carve = [&](size_t nelem) { float* p = base + off; off += (nelem + 3) & ~(size_t)3; return p; };
  float* h        = carve((size_t)N * 128);   // also aliases bucket staging during prep
  float* x2       = carve((size_t)N * 64);
  float* asd      = carve((size_t)N * 4);
  float* rec      = carve((size_t)E * 4);     // float4 dst-CSR records
  int*   srcnbr   = (int*)carve((size_t)E);   // src-CSR neighbor ids
  int*   rowptr_d = (int*)carve((size_t)N);
  int*   rowptr_s = (int*)carve((size_t)N);
  int*   bktcur_d = (int*)carve(256);
  int*   bktcur_s = (int*)carve(256);
  int*   bktbas_d = (int*)carve(260);
  int*   bktbas_s = (int*)carve(260);
  float* p_n      = carve((size_t)N * 5);
  float* fgn      = carve((size_t)N * 4);
  float* consts   = carve(16);
  if (off * sizeof(float) > ws_size) return;  // insufficient scratch: fail loudly

  // bucket staging aliases h (CSR build completes before gemm writes h)
  float4* stage_d = (float4*)h;                       // E * 16B
  int2*   stage_s = (int2*)(h + (size_t)E * 4);       // E * 8B  (total 24B*E <= N*128*4B)

  const int B = 256;
  const int gE  = cdiv_i(E, B);
  const int gN  = cdiv_i(N, B);
  const int gNW = cdiv_i((long long)N * 64, B);   // wave-per-node kernels

  // ---- graph prep: bucketed CSR build (both directions) ----
  hipMemsetAsync(bktcur_d, 0, 256 * 4, stream);
  hipMemsetAsync(bktcur_s, 0, 256 * 4, stream);
  k_prep_consts<<<1, 64, 0, stream>>>(We1, atte1, We2, atte2, nodefw, edgefw, bec, consts);
  k_bkt_hist<<<256, 256, 0, stream>>>(src, dst, bktcur_d, bktcur_s, nbkt, E);
  k_bkt_scan<<<1, 256, 0, stream>>>(bktcur_d, bktbas_d, bktcur_s, bktbas_s, nbkt);
  k_bkt_scatter<<<cdiv_i(E, 256 * CBK), 256, 0, stream>>>(src, dst, eattr, bktcur_d, bktcur_s,
                                                          stage_d, stage_s, nbkt, E);
  k_bkt_sort_d<<<nbkt, 256, 0, stream>>>(stage_d, bktbas_d, rowptr_d, (float4*)rec, N);
  k_bkt_sort_s<<<nbkt, 256, 0, stream>>>(stage_s, bktbas_s, rowptr_s, srcnbr, N);

  // ---- GAT layer 1 ----
  k_gemm<128><<<cdiv_i(N, 32), 256, 0, stream>>>(x, W1, h, N);
  k_att_nodes<<<gNW, B, 0, stream>>>(h, atts1, attd1, asd, N);
  k_gat_pull<true><<<cdiv_i(N, 4), 256, 0, stream>>>(rowptr_d, (const float4*)rec, asd, h,
                                                     consts, b1, x2, N, E);

  // ---- GAT layer 2 ----
  k_gemm<64><<<cdiv_i(N, 32), 256, 0, stream>>>(x2, W2, h, N);
  k_att_nodes<<<gNW, B, 0, stream>>>(h, atts2, attd2, asd, N);
  k_gat_pull<false><<<cdiv_i(N, 4), 256, 0, stream>>>(rowptr_d, (const float4*)rec, asd, h,
                                                      consts + 4, b2, x2, N, E);

  // ---- heads ----
  k_head<<<gNW, B, 0, stream>>>(x2, Wn, bn, Wec, p_n, fgn, N);

  // ---- factor graph: 2 pull iterations + edge output ----
  k_fg_pull<1><<<gN, B, 0, stream>>>(rowptr_d, (const float4*)rec, rowptr_s, srcnbr,
                                     p_n, fgn, consts, nullptr, N, E);
  k_fg_pull<2><<<gN, B, 0, stream>>>(rowptr_d, (const float4*)rec, rowptr_s, srcnbr,
                                     p_n, fgn, consts, out_n, N, E);
  k_fg_edge_out<<<gE, B, 0, stream>>>(src, dst, fgn, consts, out_e, E);
}

// Round 6
// 362.982 us; speedup vs baseline: 3.5360x; 1.1936x over previous
//
#include <hip/hip_runtime.h>
#include <math.h>

// GraphRespiratory: 2-layer GAT (edge features, concat=False) + factor graph.
// N=50000, E=800000, IN=128, HID=OUT=64, H=2, NC=5, EC=2, NUM_ITER=2, GAMMA=1.
//
// R5 changes vs R4:
//  - Neighbor gather operand packed bf16: h16[n][64] = (head0,head1) in one u32
//    -> 4B/lane/edge (was 8B), 12.8MB table (was 25.6MB). Attention logits and
//    self-loop row still use f32 h (denominators exact).
//  - CSR record shrunk to int2 {src, bf16x2(eattr)} = 8B/edge (was 16B).
//  - Broadcast loop 4-way unrolled (4 independent gathers in flight).
//  - k_head fused into k_gat_pull<layer2> epilogue (final emb never stored).

static inline int cdiv_i(long long a, long long b) { return (int)((a + b - 1) / b); }

#define BSH 8           // bucket shift: 256 nodes per bucket
#define CBK 8           // edges per thread in bucket scatter (2048/block)

__device__ __forceinline__ unsigned pack_bf2(float a, float b) {
  unsigned ua = __float_as_uint(a), ub = __float_as_uint(b);
  unsigned ra = (ua + 0x7fffu + ((ua >> 16) & 1u)) >> 16;
  unsigned rb = (ub + 0x7fffu + ((ub >> 16) & 1u)) & 0xffff0000u;
  return ra | rb;
}
__device__ __forceinline__ float bf_lo(unsigned v) { return __uint_as_float(v << 16); }
__device__ __forceinline__ float bf_hi(unsigned v) { return __uint_as_float(v & 0xffff0000u); }

// consts: [0..3] w_e1[h][k], [4..7] w_e2[h][k], [8] avg_ef, [9] avg_nf, [10] dbec
__global__ void k_prep_consts(const float* __restrict__ We1, const float* __restrict__ att_e1,
                              const float* __restrict__ We2, const float* __restrict__ att_e2,
                              const float* __restrict__ node_fw, const float* __restrict__ edge_fw,
                              const float* __restrict__ bec, float* __restrict__ consts) {
  if (blockIdx.x != 0 || threadIdx.x != 0) return;
  for (int h = 0; h < 2; ++h) {
    for (int k = 0; k < 2; ++k) {
      float s1 = 0.f, s2 = 0.f;
      for (int c = 0; c < 64; ++c) {
        s1 += We1[k * 128 + h * 64 + c] * att_e1[h * 64 + c];
        s2 += We2[k * 128 + h * 64 + c] * att_e2[h * 64 + c];
      }
      consts[h * 2 + k] = s1;
      consts[4 + h * 2 + k] = s2;
    }
  }
  float ef = 0.f;                      // edge_fw is [EC=2, NC=5]; mean of [1:,1:]
  for (int j = 1; j < 5; ++j) ef += edge_fw[5 + j];
  consts[8] = ef * 0.25f;
  float nf = 0.f;                      // node_fw is [NC=5, EC=2]; mean of [1:,1:]
  for (int i = 1; i < 5; ++i) nf += node_fw[i * 2 + 1];
  consts[9] = nf * 0.25f;
  consts[10] = bec[1] - bec[0];
}

// ---- bucketed CSR build ----
__global__ void k_bkt_hist(const int* __restrict__ src, const int* __restrict__ dst,
                           int* __restrict__ hist_d, int* __restrict__ hist_s,
                           int nbkt, int E) {
  __shared__ int hd[256], hs[256];
  int t = threadIdx.x;
  hd[t] = 0; hs[t] = 0;
  __syncthreads();
  for (int e = blockIdx.x * blockDim.x + t; e < E; e += gridDim.x * blockDim.x) {
    atomicAdd(&hd[dst[e] >> BSH], 1);
    atomicAdd(&hs[src[e] >> BSH], 1);
  }
  __syncthreads();
  if (t < nbkt) {
    if (hd[t]) atomicAdd(&hist_d[t], hd[t]);
    if (hs[t]) atomicAdd(&hist_s[t], hs[t]);
  }
}

// one block: exclusive-scan both histograms -> bases (nbkt+1) and cursors (in place)
__global__ void k_bkt_scan(int* __restrict__ cur_d, int* __restrict__ base_d,
                           int* __restrict__ cur_s, int* __restrict__ base_s, int nbkt) {
  __shared__ int l[256];
  int t = threadIdx.x;
  int v = (t < nbkt) ? cur_d[t] : 0;
  l[t] = v; __syncthreads();
  for (int off = 1; off < 256; off <<= 1) {
    int x = (t >= off) ? l[t - off] : 0; __syncthreads();
    l[t] += x; __syncthreads();
  }
  int incl = l[t];
  if (t < nbkt) { base_d[t] = incl - v; cur_d[t] = incl - v; }
  if (t == nbkt - 1) base_d[nbkt] = incl;
  __syncthreads();
  v = (t < nbkt) ? cur_s[t] : 0;
  l[t] = v; __syncthreads();
  for (int off = 1; off < 256; off <<= 1) {
    int x = (t >= off) ? l[t - off] : 0; __syncthreads();
    l[t] += x; __syncthreads();
  }
  incl = l[t];
  if (t < nbkt) { base_s[t] = incl - v; cur_s[t] = incl - v; }
  if (t == nbkt - 1) base_s[nbkt] = incl;
}

// block-staged bucket scatter: 2048 edges/block in regs; LDS per-bucket counts;
// one global atomicAdd per (bucket,block) to reserve; chunky tail writes.
__global__ __launch_bounds__(256)
void k_bkt_scatter(const int* __restrict__ src, const int* __restrict__ dst,
                   const float* __restrict__ eattr2,
                   int* __restrict__ cur_d, int* __restrict__ cur_s,
                   int4* __restrict__ stage_d, int2* __restrict__ stage_s,
                   int nbkt, int E) {
  __shared__ int cd[256], cs[256], bd[256], bs[256];
  int t = threadIdx.x;
  cd[t] = 0; cs[t] = 0;
  __syncthreads();
  int base = blockIdx.x * 256 * CBK;
  int s[CBK], d[CBK]; unsigned ep[CBK];
#pragma unroll
  for (int c = 0; c < CBK; ++c) {
    int e = base + c * 256 + t;
    if (e < E) {
      s[c] = src[e]; d[c] = dst[e];
      float2 ev = *(const float2*)&eattr2[2 * e];
      ep[c] = pack_bf2(ev.x, ev.y);
      atomicAdd(&cd[d[c] >> BSH], 1);
      atomicAdd(&cs[s[c] >> BSH], 1);
    } else s[c] = -1;
  }
  __syncthreads();
  if (t < nbkt) {
    bd[t] = cd[t] ? atomicAdd(&cur_d[t], cd[t]) : 0;
    bs[t] = cs[t] ? atomicAdd(&cur_s[t], cs[t]) : 0;
    cd[t] = 0; cs[t] = 0;
  }
  __syncthreads();
#pragma unroll
  for (int c = 0; c < CBK; ++c) {
    if (s[c] < 0) continue;
    int db = d[c] >> BSH, sb = s[c] >> BSH;
    int pos = bd[db] + atomicAdd(&cd[db], 1);
    stage_d[pos] = make_int4(s[c], d[c], (int)ep[c], 0);
    int pos2 = bs[sb] + atomicAdd(&cs[sb], 1);
    stage_s[pos2] = make_int2(s[c], d[c]);
  }
}

// per-bucket counting sort (dst side): emits rowptr_d + final rec {src, bf16x2 eattr}.
__global__ __launch_bounds__(256)
void k_bkt_sort_d(const int4* __restrict__ stage, const int* __restrict__ base,
                  int* __restrict__ rowptr, int2* __restrict__ rec, int N) {
  int b = blockIdx.x, t = threadIdx.x;
  int nlo = b << BSH;
  int b0 = base[b], b1 = base[b + 1];
  __shared__ int cnt[256], cur[256], l[256];
  cnt[t] = 0;
  __syncthreads();
  for (int j = b0 + t; j < b1; j += 256)
    atomicAdd(&cnt[stage[j].y - nlo], 1);
  __syncthreads();
  int v = cnt[t];
  l[t] = v; __syncthreads();
  for (int off = 1; off < 256; off <<= 1) {
    int x = (t >= off) ? l[t - off] : 0; __syncthreads();
    l[t] += x; __syncthreads();
  }
  int excl = l[t] - v;
  if (nlo + t < N) rowptr[nlo + t] = b0 + excl;
  cur[t] = excl;
  __syncthreads();
  for (int j = b0 + t; j < b1; j += 256) {
    int4 r = stage[j];
    int pos = b0 + atomicAdd(&cur[r.y - nlo], 1);
    rec[pos] = make_int2(r.x, r.z);
  }
}

// per-bucket counting sort (src side): emits rowptr_s + srcnbr (payload = dst).
__global__ __launch_bounds__(256)
void k_bkt_sort_s(const int2* __restrict__ stage, const int* __restrict__ base,
                  int* __restrict__ rowptr, int* __restrict__ srcnbr, int N) {
  int b = blockIdx.x, t = threadIdx.x;
  int nlo = b << BSH;
  int b0 = base[b], b1 = base[b + 1];
  __shared__ int cnt[256], cur[256], l[256];
  cnt[t] = 0;
  __syncthreads();
  for (int j = b0 + t; j < b1; j += 256)
    atomicAdd(&cnt[stage[j].x - nlo], 1);
  __syncthreads();
  int v = cnt[t];
  l[t] = v; __syncthreads();
  for (int off = 1; off < 256; off <<= 1) {
    int x = (t >= off) ? l[t - off] : 0; __syncthreads();
    l[t] += x; __syncthreads();
  }
  int excl = l[t] - v;
  if (nlo + t < N) rowptr[nlo + t] = b0 + excl;
  cur[t] = excl;
  __syncthreads();
  for (int j = b0 + t; j < b1; j += 256) {
    int2 r = stage[j];
    int pos = b0 + atomicAdd(&cur[r.x - nlo], 1);
    srcnbr[pos] = r.y;
  }
}

// C[N,*] = A[N,K] @ W[K,128], f32; output stored INTERLEAVED: C[n*128 + 2*c + head]
template<int K>
__global__ __launch_bounds__(256)
void k_gemm(const float* __restrict__ A, const float* __restrict__ W,
            float* __restrict__ C, int N) {
  __shared__ float Wl[K * 128];
  __shared__ float Al[32 * K];
  int tid = threadIdx.x;
  for (int i = tid * 4; i < K * 128; i += 256 * 4)
    *(float4*)&Wl[i] = *(const float4*)&W[i];
  int row0 = blockIdx.x * 32;
  for (int i = tid * 4; i < 32 * K; i += 256 * 4) {
    int r = i / K, c = i % K;
    int gr = row0 + r;
    float4 v = make_float4(0.f, 0.f, 0.f, 0.f);
    if (gr < N) v = *(const float4*)&A[(long long)gr * K + c];
    *(float4*)&Al[r * K + c] = v;
  }
  __syncthreads();
  int col = tid & 127;
  int ocol = ((col & 63) << 1) + (col >> 6);  // interleaved output column
  int rbase = (tid >> 7) * 16;
  float acc[16];
#pragma unroll
  for (int r = 0; r < 16; ++r) acc[r] = 0.f;
  for (int k = 0; k < K; ++k) {
    float w = Wl[k * 128 + col];
#pragma unroll
    for (int r = 0; r < 16; ++r) acc[r] += Al[(rbase + r) * K + k] * w;
  }
#pragma unroll
  for (int r = 0; r < 16; ++r) {
    int gr = row0 + rbase + r;
    if (gr < N) C[(long long)gr * 128 + ocol] = acc[r];
  }
}

// per-node attention scalars packed asd[n]={as0,as1,ad0,ad1} + bf16-pack h16.
// h interleaved: h[n*128 + 2*lane] = head0, +1 = head1.
__global__ void k_att_nodes(const float* __restrict__ h,
                            const float* __restrict__ atts, const float* __restrict__ attd,
                            float* __restrict__ asd, unsigned* __restrict__ h16, int N) {
  int idx = blockIdx.x * blockDim.x + threadIdx.x;
  int n = idx >> 6, lane = idx & 63;
  if (n >= N) return;
  float2 v = *(const float2*)&h[(long long)n * 128 + 2 * lane];
  h16[(n << 6) | lane] = pack_bf2(v.x, v.y);
  float ps0 = v.x * atts[lane];
  float ps1 = v.y * atts[64 + lane];
  float pd0 = v.x * attd[lane];
  float pd1 = v.y * attd[64 + lane];
  for (int off = 32; off; off >>= 1) {
    ps0 += __shfl_down(ps0, off);
    ps1 += __shfl_down(ps1, off);
    pd0 += __shfl_down(pd0, off);
    pd1 += __shfl_down(pd1, off);
  }
  if (lane == 0) {
    asd[4 * n] = ps0; asd[4 * n + 1] = ps1;
    asd[4 * n + 2] = pd0; asd[4 * n + 3] = pd1;
  }
}

// Fused GAT edge phase, pull-mode. One wave per dst node.
// HEAD: fuse classification/edge heads into the epilogue (no emb store).
template<bool RELU, bool HEAD>
__global__ __launch_bounds__(256)
void k_gat_pull(const int* __restrict__ rowptr, const int2* __restrict__ rec,
                const float* __restrict__ asd, const float* __restrict__ hf,
                const unsigned* __restrict__ h16,
                const float* __restrict__ we, const float* __restrict__ bias,
                const float* __restrict__ Wn, const float* __restrict__ bn,
                const float* __restrict__ Wec,
                float* __restrict__ out, float* __restrict__ p_n,
                float* __restrict__ fgn, int N, int E) {
  int wv = threadIdx.x >> 6, lane = threadIdx.x & 63;
  int d = blockIdx.x * 4 + wv;
  if (d >= N) return;
  int r0 = rowptr[d];
  int r1 = (d + 1 < N) ? rowptr[d + 1] : E;
  int deg = r1 - r0;
  float4 Ad = *(const float4*)&asd[4 * d];
  float w0 = we[0], w1 = we[1], w2 = we[2], w3 = we[3];
  float den0 = 0.f, den1 = 0.f, acc0 = 0.f, acc1 = 0.f, se0 = 0.f, se1 = 0.f;
  for (int cb = 0; cb < deg; cb += 64) {
    int j = cb + lane;
    int s = 0; float ea0 = 0.f, ea1 = 0.f, e0 = 0.f, e1 = 0.f;
    if (j < deg) {
      int2 rc = rec[r0 + j];
      s = rc.x;
      unsigned ep = (unsigned)rc.y;
      e0 = bf_lo(ep); e1 = bf_hi(ep);
      float4 As = *(const float4*)&asd[4 * s];
      float x0 = As.x + Ad.z + e0 * w0 + e1 * w1;
      float x1 = As.y + Ad.w + e0 * w2 + e1 * w3;
      x0 = x0 >= 0.f ? x0 : 0.2f * x0;
      x1 = x1 >= 0.f ? x1 : 0.2f * x1;
      ea0 = expf(x0); ea1 = expf(x1);
    }
    float t0 = ea0, t1 = ea1, t2 = e0, t3 = e1;
    for (int off = 32; off; off >>= 1) {
      t0 += __shfl_xor(t0, off); t1 += __shfl_xor(t1, off);
      t2 += __shfl_xor(t2, off); t3 += __shfl_xor(t3, off);
    }
    den0 += t0; den1 += t1; se0 += t2; se1 += t3;
    int m = min(64, deg - cb);
    int j2 = 0;
    for (; j2 + 4 <= m; j2 += 4) {
      int s0 = __shfl(s, j2), s1 = __shfl(s, j2 + 1);
      int s2 = __shfl(s, j2 + 2), s3 = __shfl(s, j2 + 3);
      unsigned q0 = h16[(s0 << 6) | lane];
      unsigned q1 = h16[(s1 << 6) | lane];
      unsigned q2 = h16[(s2 << 6) | lane];
      unsigned q3 = h16[(s3 << 6) | lane];
      float a00 = __shfl(ea0, j2),     a01 = __shfl(ea1, j2);
      float a10 = __shfl(ea0, j2 + 1), a11 = __shfl(ea1, j2 + 1);
      float a20 = __shfl(ea0, j2 + 2), a21 = __shfl(ea1, j2 + 2);
      float a30 = __shfl(ea0, j2 + 3), a31 = __shfl(ea1, j2 + 3);
      acc0 += a00 * bf_lo(q0); acc1 += a01 * bf_hi(q0);
      acc0 += a10 * bf_lo(q1); acc1 += a11 * bf_hi(q1);
      acc0 += a20 * bf_lo(q2); acc1 += a21 * bf_hi(q2);
      acc0 += a30 * bf_lo(q3); acc1 += a31 * bf_hi(q3);
    }
    for (; j2 < m; ++j2) {
      int sj = __shfl(s, j2);
      unsigned q = h16[(sj << 6) | lane];
      acc0 += __shfl(ea0, j2) * bf_lo(q);
      acc1 += __shfl(ea1, j2) * bf_hi(q);
    }
  }
  // self-loop: edge_attr = mean of incident (by dst) eattr; h row from f32.
  float id = 1.0f / fmaxf((float)deg, 1.0f);
  float le0 = se0 * id, le1 = se1 * id;
  float x0 = Ad.x + Ad.z + le0 * w0 + le1 * w1;
  float x1 = Ad.y + Ad.w + le0 * w2 + le1 * w3;
  x0 = x0 >= 0.f ? x0 : 0.2f * x0;
  x1 = x1 >= 0.f ? x1 : 0.2f * x1;
  float eas0 = expf(x0), eas1 = expf(x1);
  den0 += eas0; den1 += eas1;
  float2 hd = *(const float2*)&hf[(long long)d * 128 + 2 * lane];
  acc0 += eas0 * hd.x;
  acc1 += eas1 * hd.y;
  float v = 0.5f * (acc0 / (den0 + 1e-16f) + acc1 / (den1 + 1e-16f)) + bias[lane];
  if (HEAD) {
    float pv[7];
#pragma unroll
    for (int j = 0; j < 5; ++j) pv[j] = v * Wn[lane * 5 + j];
    pv[5] = v * Wec[lane * 2];
    pv[6] = v * Wec[lane * 2 + 1];
    for (int off = 32; off; off >>= 1) {
#pragma unroll
      for (int j = 0; j < 7; ++j) pv[j] += __shfl_down(pv[j], off);
    }
    if (lane == 0) {
      float l[5]; float m = -1e30f;
#pragma unroll
      for (int j = 0; j < 5; ++j) { l[j] = pv[j] + bn[j]; m = fmaxf(m, l[j]); }
      float ssum = 0.f;
#pragma unroll
      for (int j = 0; j < 5; ++j) { l[j] = expf(l[j] - m); ssum += l[j]; }
      float inv = 1.0f / ssum;
#pragma unroll
      for (int j = 0; j < 5; ++j) p_n[5 * d + j] = l[j] * inv;
      fgn[4 * d]     = pv[6] - pv[5];          // q = r1 - r0
      fgn[4 * d + 1] = (ssum - l[0]) * inv;    // nab0 = 1 - p_n[:,0]
      fgn[4 * d + 2] = 0.f;
      fgn[4 * d + 3] = 0.f;
    }
  } else {
    if (RELU) v = fmaxf(v, 0.f);
    out[(long long)d * 64 + lane] = v;
  }
}

// eab after iteration chain: 1 / (1 + exp(-t)/c), c = prod of factors.
__device__ __forceinline__ float fg_eab(float t, float c) {
  return 1.0f / (1.0f + expf(-t) / c);
}

// factor-graph node-pull iteration. One thread per node.
template<int ITER>
__global__ void k_fg_pull(const int* __restrict__ rowptr_d, const int2* __restrict__ rec,
                          const int* __restrict__ rowptr_s, const int* __restrict__ srcnbr,
                          float* __restrict__ p_n, float* __restrict__ fgn,
                          const float* __restrict__ consts, float* __restrict__ out_n,
                          int N, int E) {
  int n = blockIdx.x * blockDim.x + threadIdx.x;
  if (n >= N) return;
  float4 F = *(const float4*)&fgn[4 * n];
  float q = F.x, nab0 = F.y, nab1 = F.z;
  float avg_ef = consts[8], avg_nf = consts[9], dbec = consts[10];
  int rd0 = rowptr_d[n], rd1 = (n + 1 < N) ? rowptr_d[n + 1] : E;
  int rs0 = rowptr_s[n], rs1 = (n + 1 < N) ? rowptr_s[n + 1] : E;
  float s_eab = 0.f;
  for (int j = rd0; j < rd1; ++j) {
    float4 Fo = *(const float4*)&fgn[4 * rec[j].x];
    float t = 0.5f * (q + Fo.x) + dbec;
    float c = 1.0f + fmaxf(nab0, Fo.y) * avg_ef;
    if (ITER == 2) c *= 1.0f + fmaxf(nab1, Fo.z) * avg_ef;
    s_eab += fg_eab(t, c);
  }
  for (int j = rs0; j < rs1; ++j) {
    float4 Fo = *(const float4*)&fgn[4 * srcnbr[j]];
    float t = 0.5f * (q + Fo.x) + dbec;
    float c = 1.0f + fmaxf(nab0, Fo.y) * avg_ef;
    if (ITER == 2) c *= 1.0f + fmaxf(nab1, Fo.z) * avg_ef;
    s_eab += fg_eab(t, c);
  }
  float deg = (float)((rd1 - rd0) + (rs1 - rs0));
  float mean = s_eab / (deg + 1e-6f);
  float f = 1.0f + mean * avg_nf;
  float p0 = p_n[5 * n], p1 = p_n[5 * n + 1], p2 = p_n[5 * n + 2],
        p3 = p_n[5 * n + 3], p4 = p_n[5 * n + 4];
  float rest = (p1 + p2 + p3 + p4) * f;
  float inv = 1.0f / (p0 + rest);
  if (ITER == 1) {
    p_n[5 * n]     = p0 * inv;
    p_n[5 * n + 1] = p1 * f * inv;
    p_n[5 * n + 2] = p2 * f * inv;
    p_n[5 * n + 3] = p3 * f * inv;
    p_n[5 * n + 4] = p4 * f * inv;
    fgn[4 * n + 2] = rest * inv;   // nab1 = 1 - p0'
  } else {
    out_n[5 * n]     = logf(p0 * inv + 1e-9f);
    out_n[5 * n + 1] = logf(p1 * f * inv + 1e-9f);
    out_n[5 * n + 2] = logf(p2 * f * inv + 1e-9f);
    out_n[5 * n + 3] = logf(p3 * f * inv + 1e-9f);
    out_n[5 * n + 4] = logf(p4 * f * inv + 1e-9f);
  }
}

// final edge output: recompute full odds-chain, write log p_e^2. Coalesced.
__global__ void k_fg_edge_out(const int* __restrict__ src, const int* __restrict__ dst,
                              const float* __restrict__ fgn, const float* __restrict__ consts,
                              float* __restrict__ out_e, int E) {
  int e = blockIdx.x * blockDim.x + threadIdx.x;
  if (e >= E) return;
  float avg_ef = consts[8], dbec = consts[10];
  float4 Fs = *(const float4*)&fgn[4 * src[e]];
  float4 Fd = *(const float4*)&fgn[4 * dst[e]];
  float t = 0.5f * (Fs.x + Fd.x) + dbec;
  float c = (1.0f + fmaxf(Fs.y, Fd.y) * avg_ef) * (1.0f + fmaxf(Fs.z, Fd.z) * avg_ef);
  float pe1 = 1.0f / (1.0f + expf(-t) / c);
  float pe0 = 1.0f / (1.0f + c * expf(t));
  *(float2*)&out_e[2 * e] = make_float2(logf(pe0 + 1e-9f), logf(pe1 + 1e-9f));
}

extern "C" void kernel_launch(void* const* d_in, const int* in_sizes, int n_in,
                              void* d_out, int out_size, void* d_ws, size_t ws_size,
                              hipStream_t stream) {
  const float* x      = (const float*)d_in[0];
  const int*   ei     = (const int*)d_in[1];
  const float* eattr  = (const float*)d_in[2];
  const float* W1     = (const float*)d_in[3];
  const float* atts1  = (const float*)d_in[4];
  const float* attd1  = (const float*)d_in[5];
  const float* We1    = (const float*)d_in[6];
  const float* atte1  = (const float*)d_in[7];
  const float* b1     = (const float*)d_in[8];
  const float* W2     = (const float*)d_in[9];
  const float* atts2  = (const float*)d_in[10];
  const float* attd2  = (const float*)d_in[11];
  const float* We2    = (const float*)d_in[12];
  const float* atte2  = (const float*)d_in[13];
  const float* b2     = (const float*)d_in[14];
  const float* Wn     = (const float*)d_in[15];
  const float* bn     = (const float*)d_in[16];
  const float* Wec    = (const float*)d_in[17];
  const float* bec    = (const float*)d_in[18];
  const float* nodefw = (const float*)d_in[19];
  const float* edgefw = (const float*)d_in[20];

  const int N = in_sizes[0] / 128;
  const int E = in_sizes[1] / 2;
  const int* src = ei;
  const int* dst = ei + E;
  const int nbkt = (N + 255) >> BSH;   // 196 (assumes N <= 65536)

  float* out_n = (float*)d_out;
  float* out_e = out_n + (long long)N * 5;

  // ---- workspace carve (f32 units, 16B aligned) ----
  size_t off = 0;
  float* base = (float*)d_ws;
  auto carve = [&](size_t nelem) { float* p = base + off; off += (nelem + 3) & ~(size_t)3; return p; };
  float*    h        = carve((size_t)N * 128);   // aliases bucket staging during prep
  unsigned* h16      = (unsigned*)carve((size_t)N * 64);
  float*    x2       = carve((size_t)N * 64);
  float*    asd      = carve((size_t)N * 4);
  int2*     rec      = (int2*)carve((size_t)E * 2);   // {src, bf16x2 eattr}
  int*      srcnbr   = (int*)carve((size_t)E);
  int*      rowptr_d = (int*)carve((size_t)N);
  int*      rowptr_s = (int*)carve((size_t)N);
  int*      bktcur_d = (int*)carve(256);
  int*      bktcur_s = (int*)carve(256);
  int*      bktbas_d = (int*)carve(260);
  int*      bktbas_s = (int*)carve(260);
  float*    p_n      = carve((size_t)N * 5);
  float*    fgn      = carve((size_t)N * 4);
  float*    consts   = carve(16);
  if (off * sizeof(float) > ws_size) return;  // insufficient scratch: fail loudly

  // bucket staging aliases h (CSR build completes before gemm writes h)
  int4* stage_d = (int4*)h;                         // E * 16B
  int2* stage_s = (int2*)(h + (size_t)E * 4);       // E * 8B (24B*E <= N*128*4B)

  const int B = 256;
  const int gE  = cdiv_i(E, B);
  const int gN  = cdiv_i(N, B);
  const int gNW = cdiv_i((long long)N * 64, B);

  // ---- graph prep: bucketed CSR build (both directions) ----
  hipMemsetAsync(bktcur_d, 0, 256 * 4, stream);
  hipMemsetAsync(bktcur_s, 0, 256 * 4, stream);
  k_prep_consts<<<1, 64, 0, stream>>>(We1, atte1, We2, atte2, nodefw, edgefw, bec, consts);
  k_bkt_hist<<<256, 256, 0, stream>>>(src, dst, bktcur_d, bktcur_s, nbkt, E);
  k_bkt_scan<<<1, 256, 0, stream>>>(bktcur_d, bktbas_d, bktcur_s, bktbas_s, nbkt);
  k_bkt_scatter<<<cdiv_i(E, 256 * CBK), 256, 0, stream>>>(src, dst, eattr, bktcur_d, bktcur_s,
                                                          stage_d, stage_s, nbkt, E);
  k_bkt_sort_d<<<nbkt, 256, 0, stream>>>(stage_d, bktbas_d, rowptr_d, rec, N);
  k_bkt_sort_s<<<nbkt, 256, 0, stream>>>(stage_s, bktbas_s, rowptr_s, srcnbr, N);

  // ---- GAT layer 1 ----
  k_gemm<128><<<cdiv_i(N, 32), 256, 0, stream>>>(x, W1, h, N);
  k_att_nodes<<<gNW, B, 0, stream>>>(h, atts1, attd1, asd, h16, N);
  k_gat_pull<true, false><<<cdiv_i(N, 4), 256, 0, stream>>>(
      rowptr_d, rec, asd, h, h16, consts, b1,
      nullptr, nullptr, nullptr, x2, nullptr, nullptr, N, E);

  // ---- GAT layer 2 (+ fused heads) ----
  k_gemm<64><<<cdiv_i(N, 32), 256, 0, stream>>>(x2, W2, h, N);
  k_att_nodes<<<gNW, B, 0, stream>>>(h, atts2, attd2, asd, h16, N);
  k_gat_pull<false, true><<<cdiv_i(N, 4), 256, 0, stream>>>(
      rowptr_d, rec, asd, h, h16, consts + 4, b2,
      Wn, bn, Wec, nullptr, p_n, fgn, N, E);

  // ---- factor graph: 2 pull iterations + edge output ----
  k_fg_pull<1><<<gN, B, 0, stream>>>(rowptr_d, rec, rowptr_s, srcnbr,
                                     p_n, fgn, consts, nullptr, N, E);
  k_fg_pull<2><<<gN, B, 0, stream>>>(rowptr_d, rec, rowptr_s, srcnbr,
                                     p_n, fgn, consts, out_n, N, E);
  k_fg_edge_out<<<gE, B, 0, stream>>>(src, dst, fgn, consts, out_e, E);
}